// Round 2
// baseline (475.888 us; speedup 1.0000x reference)
//
#include <hip/hip_runtime.h>
#include <hip/hip_cooperative_groups.h>

namespace cg = cooperative_groups;

typedef unsigned int u32;
typedef unsigned short u16;
typedef __attribute__((ext_vector_type(8))) short bf16x8;   // 8 bf16 in 4 VGPRs
typedef __attribute__((ext_vector_type(4))) float f32x4;

#define NPTS 4096
#define DIM  64
#define NB   32          // 4096/128
#define NBLK 528         // NB*(NB+1)/2 upper-tri 128x128 blocks
#define WLO16 0x4140u    // window low: float bits 0x41400000 = 12.0
#define NWBIN 832        // t16 in [0x4140, 0x4480) -> D in [12, 1024)
#define RSTR 836         // histogram stride in u32 (834 bins + pad)
// full-matrix ranks: diag(4096 zeros) + doubled upper-tri; m_ut = 8386560
#define KF1C 8390654u
#define KF2C 8390656u

// Swizzled fragment-major layout (chunk = bf16x8 = 16 B):
//   chunk_index(row, f) = (row>>4)*128 + f*16 + (row&15)

// map linear upper-tri block id -> (by,bx), bx>=by
__device__ __forceinline__ void bmap(int b, int& by, int& bx){
  by = 0;
  while (b >= NB - by){ b -= NB - by; by++; }
  bx = by + b;
}

// fp32 -> bf16 bits, round-nearest-even
__device__ __forceinline__ u16 f2bf(float x){
  u32 u = __float_as_uint(x);
  return (u16)((u + 0x7fffu + ((u>>16)&1u)) >> 16);
}

// ---------- wave-parallel regularized lower incomplete gamma P(a,x) ----------
__device__ double gammainc_wave(double a, double x, double lga, int lane){
  double C = 1.0/a;
  double psum = 0.0;
  for (int b=0;b<8192;b++){
    double k = (double)(b*64 + lane + 1);
    double rr = x/(a+k);
    double pp = rr;
#pragma unroll
    for (int s=1;s<64;s<<=1){
      double t = __shfl_up(pp, s, 64);
      if (lane >= s) pp *= t;
    }
    double c = C*pp;
    psum += c;
    double clast = __shfl(c, 63, 64);
    double rlast = __shfl(rr, 63, 64);
    C = clast;
    if (rlast < 1.0 && clast*rlast/(1.0-rlast) < 1e-17) break;
  }
#pragma unroll
  for (int s=1;s<64;s<<=1) psum += __shfl_xor(psum, s, 64);
  double total = 1.0/a + psum;
  return exp(-x + a*log(x) - lga) * total;
}

// ===================== single cooperative kernel: all phases =====================
__global__ __launch_bounds__(256,2) void hsic_all(
    const float* __restrict__ X, const float* __restrict__ Y,
    u16* __restrict__ Xbf, float* __restrict__ Gall,
    u32* __restrict__ histsum, double* __restrict__ rowK, double* __restrict__ rowL,
    double* __restrict__ sums, float* __restrict__ scal, double* __restrict__ partials,
    float* __restrict__ out)
{
  cg::grid_group grid = cg::this_grid();
  const int tid = threadIdx.x;
  const int bid = blockIdx.x;
  const int gsz = gridDim.x;
  const int w = tid>>6, lane = tid&63, q = lane>>4, nl = lane&15;
  const int gtid = bid*256 + tid;
  const int gstr = gsz*256;

  __shared__ union {
    u32 lh[RSTR];                                                        // hist
    struct { double rowacc[128]; double colLDS[4][128]; double tred[2]; } rs;  // rowsum
    struct { u32 wsum[4]; double svals[2]; } sc;                         // scan
    struct { double red[4][3]; } fr;                                     // final reduce
    struct { double red2[3][4]; double tot[4]; } fz;                     // finalize
  } sh;

  // ---------------- P0: convert to swizzled bf16 + norms; zero accumulators ----------------
  for (int t = gtid; t < 4*NPTS; t += gstr){
    int rid = t >> 1, hf = t & 1;
    int z = rid >> 12, row = rid & 4095;
    const float* src = (z ? Y : X) + (size_t)row*DIM + hf*32;
    u16* basep = Xbf + ((size_t)z*32768 + (size_t)(row>>4)*128 + (row&15))*8;
    float g = 0.f;
#pragma unroll
    for (int f=0; f<4; f++){
      float4 f0 = *(const float4*)(src + f*8);
      float4 f1 = *(const float4*)(src + f*8 + 4);
      g = fmaf(f0.x,f0.x,g); g = fmaf(f0.y,f0.y,g); g = fmaf(f0.z,f0.z,g); g = fmaf(f0.w,f0.w,g);
      g = fmaf(f1.x,f1.x,g); g = fmaf(f1.y,f1.y,g); g = fmaf(f1.z,f1.z,g); g = fmaf(f1.w,f1.w,g);
      ushort4 h0, h1;
      h0.x=f2bf(f0.x); h0.y=f2bf(f0.y); h0.z=f2bf(f0.z); h0.w=f2bf(f0.w);
      h1.x=f2bf(f1.x); h1.y=f2bf(f1.y); h1.z=f2bf(f1.z); h1.w=f2bf(f1.w);
      u16* dst = basep + (size_t)(hf*4 + f)*16*8;
      *(ushort4*)dst = h0;
      *(ushort4*)(dst+4) = h1;
    }
    g += __shfl_xor(g, 1, 64);               // combine the two half-row partials
    if (hf==0) Gall[rid] = g;
  }
  for (int t = gtid; t < NPTS; t += gstr){ rowK[t]=0.0; rowL[t]=0.0; }
  for (int t = gtid; t < 2*RSTR; t += gstr) histsum[t]=0u;
  if (gtid==0){ sums[0]=0.0; sums[1]=0.0; }
  __threadfence(); grid.sync(); __threadfence();

  // ---------------- P1: upper-tri block histogram (x2 off-diag) ----------------
  for (int tile = bid; tile < 2*NBLK; tile += gsz){
    int z = (tile >= NBLK) ? 1 : 0;
    int b = tile - (z ? NBLK : 0);
    int by,bx; bmap(b,by,bx);
    bool isdiag = (by==bx);
    u32 wgt = isdiag ? 1u : 2u;
    for (int t=tid;t<RSTR;t+=256) sh.lh[t]=0;
    __syncthreads();
    const bf16x8* Xb = (const bf16x8*)Xbf + (size_t)z*32768;
    const float* Gz = Gall + z*NPTS;
    int ag0 = by*8 + w, ag1 = by*8 + 4 + w;
    bf16x8 a0f0 = Xb[ag0*128 + q*16 + nl];
    bf16x8 a0f1 = Xb[ag0*128 + (4+q)*16 + nl];
    bf16x8 a1f0 = Xb[ag1*128 + q*16 + nl];
    bf16x8 a1f1 = Xb[ag1*128 + (4+q)*16 + nl];
    float ga0 = Gz[ag0*16 + nl], ga1 = Gz[ag1*16 + nl];
    float g0m[4], g1m[4];
#pragma unroll
    for (int r=0;r<4;r++){ g0m[r] = __shfl(ga0, q*4+r, 64); g1m[r] = __shfl(ga1, q*4+r, 64); }
#pragma unroll
    for (int tb=0;tb<8;tb++){
      int jg = bx*8 + tb;
      bf16x8 bf0 = Xb[jg*128 + q*16 + nl];
      bf16x8 bf1 = Xb[jg*128 + (4+q)*16 + nl];
      f32x4 acc0 = (f32x4)0.0f, acc1 = (f32x4)0.0f;
      acc0 = __builtin_amdgcn_mfma_f32_16x16x32_bf16(a0f0, bf0, acc0, 0,0,0);
      acc0 = __builtin_amdgcn_mfma_f32_16x16x32_bf16(a0f1, bf1, acc0, 0,0,0);
      acc1 = __builtin_amdgcn_mfma_f32_16x16x32_bf16(a1f0, bf0, acc1, 0,0,0);
      acc1 = __builtin_amdgcn_mfma_f32_16x16x32_bf16(a1f1, bf1, acc1, 0,0,0);
      int j = jg*16 + nl;
      float gb = Gz[j];
#pragma unroll
      for (int r=0;r<4;r++){
        float d0 = (g0m[r] + gb) - 2.0f*acc0[r];
        float d1 = (g1m[r] + gb) - 2.0f*acc1[r];
        if (isdiag){
          if (ag0*16 + q*4 + r == j) d0 = 0.f;
          if (ag1*16 + q*4 + r == j) d1 = 0.f;
        }
        u32 t0 = __float_as_uint(d0) >> 16;
        u32 bin0 = (t0 < WLO16) ? 0u : (t0 >= WLO16+NWBIN) ? (u32)(NWBIN+1) : (t0 - WLO16 + 1u);
        atomicAdd(&sh.lh[bin0], wgt);
        u32 t1 = __float_as_uint(d1) >> 16;
        u32 bin1 = (t1 < WLO16) ? 0u : (t1 >= WLO16+NWBIN) ? (u32)(NWBIN+1) : (t1 - WLO16 + 1u);
        atomicAdd(&sh.lh[bin1], wgt);
      }
    }
    __syncthreads();
    u32* dst = histsum + (size_t)z*RSTR;
    for (int t=tid;t<RSTR;t+=256){
      u32 v = sh.lh[t];
      if (v) atomicAdd(&dst[t], v);
    }
    // no trailing sync needed: each thread re-zeroes exactly the lh entries it flushed
  }
  __threadfence(); grid.sync(); __threadfence();

  // ---------------- P2: median select + interpolate (blocks 0,1) ----------------
  if (bid < 2){
    int z = bid;
    u32 c4[4] = {0,0,0,0};
    if (tid < 209){
      const u32* base = histsum + (size_t)z*RSTR + 4*tid;
      int lim = RSTR - 4*tid;
      c4[0] = base[0];
      if (lim>1) c4[1] = base[1];
      if (lim>2) c4[2] = base[2];
      if (lim>3) c4[3] = base[3];
    }
    u32 s = c4[0]+c4[1]+c4[2]+c4[3];
    u32 pre = s;
#pragma unroll
    for (int off=1; off<64; off<<=1){
      u32 t2 = __shfl_up(pre, off, 64);
      if (lane >= off) pre += t2;
    }
    if (lane==63) sh.sc.wsum[w] = pre;
    __syncthreads();
    u32 base2 = 0;
    for (int k=0;k<w;k++) base2 += sh.sc.wsum[k];
    u32 incl = base2 + pre, excl = incl - s;
    u32 ks[2] = {KF1C,KF2C};
#pragma unroll
    for (int w2=0; w2<2; w2++){
      if (ks[w2] >= excl && ks[w2] < incl){
        u32 acc = excl;
#pragma unroll
        for (int j=0;j<4;j++){
          if (ks[w2] < acc + c4[j]){
            int b = tid*4 + j;
            double lo, hi;
            if (b==0){ lo=12.0; hi=12.0; }
            else if (b>=NWBIN+1){ lo=1024.0; hi=1024.0; }
            else {
              u32 t16 = WLO16 + (u32)b - 1u;
              lo = (double)__uint_as_float(t16<<16);
              hi = (double)__uint_as_float((t16+1u)<<16);
            }
            double frac = ((double)(ks[w2]-acc) + 0.5)/(double)c4[j];
            sh.sc.svals[w2] = lo + (hi-lo)*frac;
            break;
          }
          acc += c4[j];
        }
      }
    }
    __syncthreads();
    if (tid==0){
      float med = (float)(0.5*(sh.sc.svals[0]+sh.sc.svals[1]));
      float wd = sqrtf(0.5f*med);
      scal[z] = 2.0f*wd*wd;
    }
  }
  __threadfence(); grid.sync(); __threadfence();

  // ---------------- P3: upper-tri block row sums (row + col via symmetry) ----------------
  for (int tile = bid; tile < 2*NBLK; tile += gsz){
    int z = (tile >= NBLK) ? 1 : 0;
    int b = tile - (z ? NBLK : 0);
    int by,bx; bmap(b,by,bx);
    bool isdiag = (by==bx);
    const bf16x8* Xb = (const bf16x8*)Xbf + (size_t)z*32768;
    const float* Gz = Gall + z*NPTS;
    float negi = -1.0f/scal[z];
    int ag0 = by*8 + w, ag1 = by*8 + 4 + w;
    bf16x8 a0f0 = Xb[ag0*128 + q*16 + nl];
    bf16x8 a0f1 = Xb[ag0*128 + (4+q)*16 + nl];
    bf16x8 a1f0 = Xb[ag1*128 + q*16 + nl];
    bf16x8 a1f1 = Xb[ag1*128 + (4+q)*16 + nl];
    float ga0 = Gz[ag0*16 + nl], ga1 = Gz[ag1*16 + nl];
    float g0m[4], g1m[4];
#pragma unroll
    for (int r=0;r<4;r++){ g0m[r] = __shfl(ga0, q*4+r, 64); g1m[r] = __shfl(ga1, q*4+r, 64); }
    double rs0[4] = {0,0,0,0}, rs1[4] = {0,0,0,0};
#pragma unroll
    for (int tb=0;tb<8;tb++){
      int jg = bx*8 + tb;
      bf16x8 bf0 = Xb[jg*128 + q*16 + nl];
      bf16x8 bf1 = Xb[jg*128 + (4+q)*16 + nl];
      f32x4 acc0 = (f32x4)0.0f, acc1 = (f32x4)0.0f;
      acc0 = __builtin_amdgcn_mfma_f32_16x16x32_bf16(a0f0, bf0, acc0, 0,0,0);
      acc0 = __builtin_amdgcn_mfma_f32_16x16x32_bf16(a0f1, bf1, acc0, 0,0,0);
      acc1 = __builtin_amdgcn_mfma_f32_16x16x32_bf16(a1f0, bf0, acc1, 0,0,0);
      acc1 = __builtin_amdgcn_mfma_f32_16x16x32_bf16(a1f1, bf1, acc1, 0,0,0);
      int j = jg*16 + nl;
      float gb = Gz[j];
      double cs = 0.0;
#pragma unroll
      for (int r=0;r<4;r++){
        float d0 = (g0m[r] + gb) - 2.0f*acc0[r];
        float d1 = (g1m[r] + gb) - 2.0f*acc1[r];
        if (isdiag){
          if (ag0*16 + q*4 + r == j) d0 = 0.f;    // exact K_ii = 1
          if (ag1*16 + q*4 + r == j) d1 = 0.f;
        }
        double e0 = (double)expf(d0*negi);
        double e1 = (double)expf(d1*negi);
        rs0[r] += e0; rs1[r] += e1;
        cs += e0 + e1;
      }
      cs += __shfl_xor(cs, 16, 64);
      cs += __shfl_xor(cs, 32, 64);
      if (q==0) sh.rs.colLDS[w][tb*16 + nl] = cs;
    }
#pragma unroll
    for (int r=0;r<4;r++){
      double v0 = rs0[r], v1 = rs1[r];
      v0 += __shfl_xor(v0,1,64); v0 += __shfl_xor(v0,2,64);
      v0 += __shfl_xor(v0,4,64); v0 += __shfl_xor(v0,8,64);
      v1 += __shfl_xor(v1,1,64); v1 += __shfl_xor(v1,2,64);
      v1 += __shfl_xor(v1,4,64); v1 += __shfl_xor(v1,8,64);
      rs0[r] = v0; rs1[r] = v1;
    }
    if (nl==0){
#pragma unroll
      for (int r=0;r<4;r++){
        sh.rs.rowacc[w*16 + q*4 + r]     = rs0[r];
        sh.rs.rowacc[(4+w)*16 + q*4 + r] = rs1[r];
      }
    }
    __syncthreads();
    double tot = 0.0;
    if (tid < 128){
      double rv = sh.rs.rowacc[tid];
      double cv = sh.rs.colLDS[0][tid] + sh.rs.colLDS[1][tid] + sh.rs.colLDS[2][tid] + sh.rs.colLDS[3][tid];
      double* rowG = z ? rowL : rowK;
      atomicAdd(&rowG[by*128 + tid], rv);
      if (!isdiag) atomicAdd(&rowG[bx*128 + tid], cv);
      tot = rv + (isdiag ? 0.0 : cv);
    }
#pragma unroll
    for (int s2=1;s2<64;s2<<=1) tot += __shfl_xor(tot, s2, 64);
    if (lane==0 && w<2) sh.rs.tred[w] = tot;
    __syncthreads();
    if (tid==0) atomicAdd(&sums[z], sh.rs.tred[0] + sh.rs.tred[1]);
  }
  __threadfence(); grid.sync(); __threadfence();

  // ---------------- P4: centered products ----------------
  {
    const bf16x8* Xb = (const bf16x8*)Xbf;
    const bf16x8* Yb = Xb + 32768;
    const float* Gx = Gall;
    const float* Gy = Gall + NPTS;
    const double inv_n = 1.0/(double)NPTS;
    double tmK = sums[0]*(inv_n*inv_n), tmL = sums[1]*(inv_n*inv_n);
    float negx = -1.0f/scal[0], negy = -1.0f/scal[1];
    double S1=0, S2=0, trV=0;
    for (int t = bid; t < 2*NBLK; t += gsz){
      int b = t >> 1, half = t & 1;
      int by,bx; bmap(b,by,bx);
      bool isdiag = (by==bx);
      double wgt = isdiag ? 1.0 : 2.0;
      int ag = by*8 + half*4 + w;
      bf16x8 axf0 = Xb[ag*128 + q*16 + nl];
      bf16x8 axf1 = Xb[ag*128 + (4+q)*16 + nl];
      bf16x8 ayf0 = Yb[ag*128 + q*16 + nl];
      bf16x8 ayf1 = Yb[ag*128 + (4+q)*16 + nl];
      int rowA = ag*16 + nl;
      float gaX = Gx[rowA], gaY = Gy[rowA];
      float gXm[4], gYm[4];
#pragma unroll
      for (int r=0;r<4;r++){ gXm[r] = __shfl(gaX, q*4+r, 64); gYm[r] = __shfl(gaY, q*4+r, 64); }
      double rmKi[4], rmLi[4];
#pragma unroll
      for (int r=0;r<4;r++){
        int i = ag*16 + q*4 + r;
        rmKi[r] = rowK[i]*inv_n; rmLi[r] = rowL[i]*inv_n;
      }
#pragma unroll
      for (int tb=0;tb<8;tb++){
        int jg = bx*8 + tb;
        f32x4 accX = (f32x4)0.0f, accY = (f32x4)0.0f;
        accX = __builtin_amdgcn_mfma_f32_16x16x32_bf16(axf0, Xb[jg*128 + q*16 + nl],     accX, 0,0,0);
        accX = __builtin_amdgcn_mfma_f32_16x16x32_bf16(axf1, Xb[jg*128 + (4+q)*16 + nl], accX, 0,0,0);
        accY = __builtin_amdgcn_mfma_f32_16x16x32_bf16(ayf0, Yb[jg*128 + q*16 + nl],     accY, 0,0,0);
        accY = __builtin_amdgcn_mfma_f32_16x16x32_bf16(ayf1, Yb[jg*128 + (4+q)*16 + nl], accY, 0,0,0);
        int j = jg*16 + nl;
        float gbX = Gx[j], gbY = Gy[j];
        double cmK = rowK[j]*inv_n - tmK;
        double cmL = rowL[j]*inv_n - tmL;
#pragma unroll
        for (int r=0;r<4;r++){
          int i = ag*16 + q*4 + r;
          float dx = (gXm[r] + gbX) - 2.0f*accX[r];
          float dy = (gYm[r] + gbY) - 2.0f*accY[r];
          bool dg = isdiag && i==j;
          if (dg){ dx = 0.f; dy = 0.f; }
          float kx = expf(dx*negx);
          float lv = expf(dy*negy);
          double kc = ((double)kx - rmKi[r]) - cmK;
          double lc = ((double)lv - rmLi[r]) - cmL;
          double prod = kc*lc;
          S1 += wgt*prod;
          double vv = (prod*prod)*(1.0/36.0);
          S2 += wgt*vv;
          if (dg) trV += vv;
        }
      }
    }
    double vals[3]={S1,S2,trV};
#pragma unroll
    for (int v=0;v<3;v++){
      double x = vals[v];
#pragma unroll
      for (int s2=1;s2<64;s2<<=1) x += __shfl_xor(x, s2, 64);
      if (lane==0) sh.fr.red[w][v]=x;
    }
    __syncthreads();
    if (tid < 3)
      partials[(size_t)bid*4 + tid] = sh.fr.red[0][tid]+sh.fr.red[1][tid]+sh.fr.red[2][tid]+sh.fr.red[3][tid];
  }
  __threadfence(); grid.sync(); __threadfence();

  // ---------------- P5: reduce partials + gamma-ppf (block 0 only) ----------------
  if (bid != 0) return;
  {
    double v0=0,v1=0,v2=0;
    for (int i=tid; i<gsz; i+=256){
      const double* p = partials + (size_t)i*4;
      v0+=p[0]; v1+=p[1]; v2+=p[2];
    }
    double vals[3]={v0,v1,v2};
#pragma unroll
    for (int v=0;v<3;v++){
      double x = vals[v];
#pragma unroll
      for (int s2=1;s2<64;s2<<=1) x += __shfl_xor(x, s2, 64);
      if (lane==0) sh.fz.red2[v][w]=x;
    }
    __syncthreads();
    if (tid==0){
#pragma unroll
      for (int v=0;v<3;v++) sh.fz.tot[v] = sh.fz.red2[v][0]+sh.fz.red2[v][1]+sh.fz.red2[v][2]+sh.fz.red2[v][3];
    }
    __syncthreads();
    if (tid >= 64) return;

    const double n = (double)NPTS;
    double totK=sums[0], totL=sums[1];
    double S1=sh.fz.tot[0], S2=sh.fz.tot[1], trV=sh.fz.tot[2];
    double testStat = S1/n;
    double varHSIC = (S2 - trV)/n/(n-1.0);
    varHSIC = varHSIC*72.0*(n-4.0)*(n-5.0)/n/(n-1.0)/(n-2.0)/(n-3.0);
    double muX = (totK-n)/n/(n-1.0);   // trace(K) = n exactly (diag forced to 1)
    double muY = (totL-n)/n/(n-1.0);
    double mHSIC = (1.0 + muX*muY - muX - muY)/n;
    double al = mHSIC*mHSIC/varHSIC;
    double bet = varHSIC*n/mHSIC;
    double p = (double)((float)(1.0-0.8));
    double lga = lgamma(al);
    double lo = 0.0, hi = al + 10.0*sqrt(al) + 100.0;
    const double zp = -0.8416212335729142957;  // Phi^-1(0.2)
    double tt = 1.0 - 1.0/(9.0*al) + zp/(3.0*sqrt(al));
    double x = al*tt*tt*tt;
    if (!(x > 0.0) || !(x < hi)) x = 0.5*hi;
    for (int it=0; it<2; ++it){
      double P = gammainc_wave(al, x, lga, lane);
      double diff = P - p;
      if (diff < 0.0) lo = x; else hi = x;
      if (fabs(diff) < 1e-12) break;
      double pdf = exp(-x + (al-1.0)*log(x) - lga);
      double nx = x - diff/pdf;
      if (!(nx > lo) || !(nx < hi)) nx = 0.5*(lo+hi);
      x = nx;
    }
    if (lane==0){
      out[0]=(float)testStat;
      out[1]=(float)(bet*x);
    }
  }
}

// ---------- host ----------
extern "C" void kernel_launch(void* const* d_in, const int* in_sizes, int n_in,
                              void* d_out, int out_size, void* d_ws, size_t ws_size,
                              hipStream_t stream) {
  const float* X = (const float*)d_in[0];
  const float* Y = (const float*)d_in[1];
  float* out = (float*)d_out;
  char* ws = (char*)d_ws;

  double* sums     = (double*)ws;                    // 2 doubles @0
  float*  scal     = (float*)(ws + 128);             // 2 floats
  u32*    histsum  = (u32*)(ws + 256);               // 2*836 u32 = 6688 B
  double* rowK     = (double*)(ws + 8192);           // 32 KB
  double* rowL     = (double*)(ws + 40960);          // 32 KB
  float*  Gall     = (float*)(ws + 73728);           // 32 KB
  double* partials = (double*)(ws + 106496);         // up to 1056*4 doubles = 33792 B
  u16*    Xbf      = (u16*)(ws + (4u<<20));          // 1 MB (swizzled fragment-major)
  size_t need = (size_t)(4u<<20) + (size_t)2*NPTS*DIM*2;   // ~5.2 MB

  if (ws_size < need) return;

  static int gridBlocks = 0;
  if (gridBlocks == 0){
    int dev = 0; (void)hipGetDevice(&dev);
    int nCU = 0; (void)hipDeviceGetAttribute(&nCU, hipDeviceAttributeMultiprocessorCount, dev);
    int maxb = 0;
    (void)hipOccupancyMaxActiveBlocksPerMultiprocessor(&maxb, reinterpret_cast<const void*>(hsic_all), 256, 0);
    if (nCU <= 0) nCU = 256;
    if (maxb <= 0) maxb = 1;
    long g = (long)nCU * (long)maxb;
    if (g > 2*NBLK) g = 2*NBLK;
    if (g < 2) g = 2;
    gridBlocks = (int)g;
  }

  void* args[] = {(void*)&X, (void*)&Y, (void*)&Xbf, (void*)&Gall, (void*)&histsum,
                  (void*)&rowK, (void*)&rowL, (void*)&sums, (void*)&scal,
                  (void*)&partials, (void*)&out};
  (void)hipLaunchCooperativeKernel(reinterpret_cast<const void*>(hsic_all),
                                   dim3(gridBlocks), dim3(256), args, 0, stream);
}

// Round 3
// 153.641 us; speedup vs baseline: 3.0974x; 3.0974x over previous
//
#include <hip/hip_runtime.h>

typedef unsigned int u32;
typedef unsigned short u16;
typedef __attribute__((ext_vector_type(8))) short bf16x8;   // 8 bf16 in 4 VGPRs
typedef __attribute__((ext_vector_type(4))) float f32x4;

#define NPTS 4096
#define DIM  64
#define NB   32          // 4096/128
#define NBLK 528         // NB*(NB+1)/2 upper-tri 128x128 blocks
#define WLO16 0x4140u    // window low: float bits 0x41400000 = 12.0
#define NWBIN 832        // t16 in [0x4140, 0x4480) -> D in [12, 1024)
#define RSTR 836         // histogram stride in u32 (834 bins + pad)
// full-matrix ranks: diag(4096 zeros) + doubled upper-tri; m_ut = 8386560
#define KF1C 8390654u
#define KF2C 8390656u

// Swizzled fragment-major layout (chunk = bf16x8 = 16 B):
//   chunk_index(row, f) = (row>>4)*128 + f*16 + (row&15)

// map linear upper-tri block id -> (by,bx), bx>=by
__device__ __forceinline__ void bmap(int b, int& by, int& bx){
  by = 0;
  while (b >= NB - by){ b -= NB - by; by++; }
  bx = by + b;
}

// fp32 -> bf16 bits, round-nearest-even
__device__ __forceinline__ u16 f2bf(float x){
  u32 u = __float_as_uint(x);
  return (u16)((u + 0x7fffu + ((u>>16)&1u)) >> 16);
}

// ---------- dispatch 1: convert to swizzled bf16 + norms; zero accumulators ----------
__global__ __launch_bounds__(256) void convert_k(const float* __restrict__ X, const float* __restrict__ Y,
                                                 u16* __restrict__ Xbf, float* __restrict__ Gall,
                                                 u32* __restrict__ histsum, double* __restrict__ rowK,
                                                 double* __restrict__ rowL, double* __restrict__ sumsS,
                                                 double* __restrict__ slotbuf, u32* __restrict__ ctr){
  int t = blockIdx.x*256 + threadIdx.x;     // 16384 threads, 2 per row (half-row each)
  int rid = t >> 1, hf = t & 1;
  int z = rid >> 12, row = rid & 4095;
  const float* src = (z ? Y : X) + (size_t)row*DIM + hf*32;
  u16* basep = Xbf + ((size_t)z*32768 + (size_t)(row>>4)*128 + (row&15))*8;
  float g = 0.f;
#pragma unroll
  for (int f=0; f<4; f++){
    float4 f0 = *(const float4*)(src + f*8);
    float4 f1 = *(const float4*)(src + f*8 + 4);
    g = fmaf(f0.x,f0.x,g); g = fmaf(f0.y,f0.y,g); g = fmaf(f0.z,f0.z,g); g = fmaf(f0.w,f0.w,g);
    g = fmaf(f1.x,f1.x,g); g = fmaf(f1.y,f1.y,g); g = fmaf(f1.z,f1.z,g); g = fmaf(f1.w,f1.w,g);
    ushort4 h0, h1;
    h0.x=f2bf(f0.x); h0.y=f2bf(f0.y); h0.z=f2bf(f0.z); h0.w=f2bf(f0.w);
    h1.x=f2bf(f1.x); h1.y=f2bf(f1.y); h1.z=f2bf(f1.z); h1.w=f2bf(f1.w);
    u16* dst = basep + (size_t)(hf*4 + f)*16*8;
    *(ushort4*)dst = h0;
    *(ushort4*)(dst+4) = h1;
  }
  g += __shfl_xor(g, 1, 64);               // combine the two half-row partials
  if (hf==0) Gall[rid] = g;
  // zero atomic accumulators (workspace is re-poisoned between runs)
  if (t < NPTS){ rowK[t] = 0.0; rowL[t] = 0.0; }
  if (t < 2*RSTR) histsum[t] = 0u;
  if (t < 64) slotbuf[t] = 0.0;
  if (t < 16) sumsS[t] = 0.0;
  if (t == 0) *ctr = 0u;
}

// ---------- dispatch 2: upper-tri block histogram (x2 off-diag), 4-way replicated LDS ----------
__global__ __launch_bounds__(256,2) void hist_k(const u16* __restrict__ Xbf, const float* __restrict__ Gall,
                                                u32* __restrict__ histsum){
  __shared__ u32 lh[4][RSTR];
  int z = blockIdx.y, tid = threadIdx.x;
  int by,bx; bmap(blockIdx.x, by, bx);
  bool isdiag = (by==bx);
  u32 wgt = isdiag ? 1u : 2u;
  int w=tid>>6, lane=tid&63, q=lane>>4, nl=lane&15;
  int cp = lane & 3;                       // replica copy: splits same-bin serialization 4x
  for (int t=tid;t<4*RSTR;t+=256) ((u32*)lh)[t]=0;
  __syncthreads();
  const bf16x8* Xb = (const bf16x8*)Xbf + (size_t)z*32768;
  const float* Gz = Gall + z*NPTS;
  int ag0 = by*8 + w, ag1 = by*8 + 4 + w;
  bf16x8 a0f0 = Xb[ag0*128 + q*16 + nl];
  bf16x8 a0f1 = Xb[ag0*128 + (4+q)*16 + nl];
  bf16x8 a1f0 = Xb[ag1*128 + q*16 + nl];
  bf16x8 a1f1 = Xb[ag1*128 + (4+q)*16 + nl];
  float ga0 = Gz[ag0*16 + nl], ga1 = Gz[ag1*16 + nl];
  float g0m[4], g1m[4];
#pragma unroll
  for (int r=0;r<4;r++){ g0m[r] = __shfl(ga0, q*4+r, 64); g1m[r] = __shfl(ga1, q*4+r, 64); }
#pragma unroll
  for (int tb=0;tb<8;tb++){
    int jg = bx*8 + tb;
    bf16x8 bf0 = Xb[jg*128 + q*16 + nl];
    bf16x8 bf1 = Xb[jg*128 + (4+q)*16 + nl];
    f32x4 acc0 = (f32x4)0.0f, acc1 = (f32x4)0.0f;
    acc0 = __builtin_amdgcn_mfma_f32_16x16x32_bf16(a0f0, bf0, acc0, 0,0,0);
    acc0 = __builtin_amdgcn_mfma_f32_16x16x32_bf16(a0f1, bf1, acc0, 0,0,0);
    acc1 = __builtin_amdgcn_mfma_f32_16x16x32_bf16(a1f0, bf0, acc1, 0,0,0);
    acc1 = __builtin_amdgcn_mfma_f32_16x16x32_bf16(a1f1, bf1, acc1, 0,0,0);
    int j = jg*16 + nl;
    float gb = Gz[j];
#pragma unroll
    for (int r=0;r<4;r++){
      float d0 = (g0m[r] + gb) - 2.0f*acc0[r];
      float d1 = (g1m[r] + gb) - 2.0f*acc1[r];
      if (isdiag){
        if (ag0*16 + q*4 + r == j) d0 = 0.f;
        if (ag1*16 + q*4 + r == j) d1 = 0.f;
      }
      u32 t0 = __float_as_uint(d0) >> 16;
      u32 bin0 = (t0 < WLO16) ? 0u : (t0 >= WLO16+NWBIN) ? (u32)(NWBIN+1) : (t0 - WLO16 + 1u);
      atomicAdd(&lh[cp][bin0], wgt);
      u32 t1 = __float_as_uint(d1) >> 16;
      u32 bin1 = (t1 < WLO16) ? 0u : (t1 >= WLO16+NWBIN) ? (u32)(NWBIN+1) : (t1 - WLO16 + 1u);
      atomicAdd(&lh[cp][bin1], wgt);
    }
  }
  __syncthreads();
  u32* dst = histsum + (size_t)z*RSTR;
  for (int t=tid;t<RSTR;t+=256){
    u32 v = lh[0][t] + lh[1][t] + lh[2][t] + lh[3][t];
    if (v) atomicAdd(&dst[t], v);
  }
}

// ---------- dispatch 3: per-block median scan (redundant) + upper-tri row sums ----------
__global__ __launch_bounds__(256,2) void rowsum_k(const u16* __restrict__ Xbf, const float* __restrict__ Gall,
                                                  const u32* __restrict__ histsum, float* __restrict__ scal,
                                                  double* __restrict__ rowK, double* __restrict__ rowL,
                                                  double* __restrict__ sumsS){
  __shared__ union {
    struct { u32 wsum[4]; double svals[2]; float scal_sh; } sc;
    struct { double rowacc[128]; double colLDS[4][128]; double tred[2]; } rs;
  } sh;
  int z = blockIdx.y, tid = threadIdx.x;
  int w=tid>>6, lane=tid&63, q=lane>>4, nl=lane&15;

  // --- scan prologue: compute median width from histsum (every block, ~1us, L2 hits) ---
  {
    u32 c4[4] = {0,0,0,0};
    if (tid < 209){
      const u32* base = histsum + (size_t)z*RSTR + 4*tid;
      int lim = RSTR - 4*tid;
      c4[0] = base[0];
      if (lim>1) c4[1] = base[1];
      if (lim>2) c4[2] = base[2];
      if (lim>3) c4[3] = base[3];
    }
    u32 s = c4[0]+c4[1]+c4[2]+c4[3];
    u32 pre = s;
#pragma unroll
    for (int off=1; off<64; off<<=1){
      u32 t2 = __shfl_up(pre, off, 64);
      if (lane >= off) pre += t2;
    }
    if (lane==63) sh.sc.wsum[w] = pre;
    __syncthreads();
    u32 base2 = 0;
    for (int k=0;k<w;k++) base2 += sh.sc.wsum[k];
    u32 incl = base2 + pre, excl = incl - s;
    u32 ks[2] = {KF1C,KF2C};
#pragma unroll
    for (int w2=0; w2<2; w2++){
      if (ks[w2] >= excl && ks[w2] < incl){
        u32 acc = excl;
#pragma unroll
        for (int j=0;j<4;j++){
          if (ks[w2] < acc + c4[j]){
            int b = tid*4 + j;
            double lo, hi;
            if (b==0){ lo=12.0; hi=12.0; }
            else if (b>=NWBIN+1){ lo=1024.0; hi=1024.0; }
            else {
              u32 t16 = WLO16 + (u32)b - 1u;
              lo = (double)__uint_as_float(t16<<16);
              hi = (double)__uint_as_float((t16+1u)<<16);
            }
            double frac = ((double)(ks[w2]-acc) + 0.5)/(double)c4[j];
            sh.sc.svals[w2] = lo + (hi-lo)*frac;
            break;
          }
          acc += c4[j];
        }
      }
    }
    __syncthreads();
    if (tid==0){
      float med = (float)(0.5*(sh.sc.svals[0]+sh.sc.svals[1]));
      float wd = sqrtf(0.5f*med);
      float sc2 = 2.0f*wd*wd;
      sh.sc.scal_sh = sc2;
      if (blockIdx.x==0) scal[z] = sc2;    // for final_k
    }
    __syncthreads();
  }
  float negi = -1.0f / sh.sc.scal_sh;
  __syncthreads();                          // done reading union.sc before union.rs writes

  // --- rowsum body ---
  int by,bx; bmap(blockIdx.x, by, bx);
  bool isdiag = (by==bx);
  const bf16x8* Xb = (const bf16x8*)Xbf + (size_t)z*32768;
  const float* Gz = Gall + z*NPTS;
  int ag0 = by*8 + w, ag1 = by*8 + 4 + w;
  bf16x8 a0f0 = Xb[ag0*128 + q*16 + nl];
  bf16x8 a0f1 = Xb[ag0*128 + (4+q)*16 + nl];
  bf16x8 a1f0 = Xb[ag1*128 + q*16 + nl];
  bf16x8 a1f1 = Xb[ag1*128 + (4+q)*16 + nl];
  float ga0 = Gz[ag0*16 + nl], ga1 = Gz[ag1*16 + nl];
  float g0m[4], g1m[4];
#pragma unroll
  for (int r=0;r<4;r++){ g0m[r] = __shfl(ga0, q*4+r, 64); g1m[r] = __shfl(ga1, q*4+r, 64); }
  double rs0[4] = {0,0,0,0}, rs1[4] = {0,0,0,0};
#pragma unroll
  for (int tb=0;tb<8;tb++){
    int jg = bx*8 + tb;
    bf16x8 bf0 = Xb[jg*128 + q*16 + nl];
    bf16x8 bf1 = Xb[jg*128 + (4+q)*16 + nl];
    f32x4 acc0 = (f32x4)0.0f, acc1 = (f32x4)0.0f;
    acc0 = __builtin_amdgcn_mfma_f32_16x16x32_bf16(a0f0, bf0, acc0, 0,0,0);
    acc0 = __builtin_amdgcn_mfma_f32_16x16x32_bf16(a0f1, bf1, acc0, 0,0,0);
    acc1 = __builtin_amdgcn_mfma_f32_16x16x32_bf16(a1f0, bf0, acc1, 0,0,0);
    acc1 = __builtin_amdgcn_mfma_f32_16x16x32_bf16(a1f1, bf1, acc1, 0,0,0);
    int j = jg*16 + nl;
    float gb = Gz[j];
    double cs = 0.0;
#pragma unroll
    for (int r=0;r<4;r++){
      float d0 = (g0m[r] + gb) - 2.0f*acc0[r];
      float d1 = (g1m[r] + gb) - 2.0f*acc1[r];
      if (isdiag){
        if (ag0*16 + q*4 + r == j) d0 = 0.f;    // exact K_ii = 1
        if (ag1*16 + q*4 + r == j) d1 = 0.f;
      }
      double e0 = (double)expf(d0*negi);
      double e1 = (double)expf(d1*negi);
      rs0[r] += e0; rs1[r] += e1;
      cs += e0 + e1;
    }
    cs += __shfl_xor(cs, 16, 64);
    cs += __shfl_xor(cs, 32, 64);
    if (q==0) sh.rs.colLDS[w][tb*16 + nl] = cs;
  }
#pragma unroll
  for (int r=0;r<4;r++){
    double v0 = rs0[r], v1 = rs1[r];
    v0 += __shfl_xor(v0,1,64); v0 += __shfl_xor(v0,2,64);
    v0 += __shfl_xor(v0,4,64); v0 += __shfl_xor(v0,8,64);
    v1 += __shfl_xor(v1,1,64); v1 += __shfl_xor(v1,2,64);
    v1 += __shfl_xor(v1,4,64); v1 += __shfl_xor(v1,8,64);
    rs0[r] = v0; rs1[r] = v1;
  }
  if (nl==0){
#pragma unroll
    for (int r=0;r<4;r++){
      sh.rs.rowacc[w*16 + q*4 + r]     = rs0[r];
      sh.rs.rowacc[(4+w)*16 + q*4 + r] = rs1[r];
    }
  }
  __syncthreads();
  double tot = 0.0;
  if (tid < 128){
    double rv = sh.rs.rowacc[tid];
    double cv = sh.rs.colLDS[0][tid] + sh.rs.colLDS[1][tid] + sh.rs.colLDS[2][tid] + sh.rs.colLDS[3][tid];
    double* rowG = z ? rowL : rowK;
    atomicAdd(&rowG[by*128 + tid], rv);
    if (!isdiag) atomicAdd(&rowG[bx*128 + tid], cv);
    tot = rv + (isdiag ? 0.0 : cv);
  }
#pragma unroll
  for (int s2=1;s2<64;s2<<=1) tot += __shfl_xor(tot, s2, 64);
  if (lane==0 && w<2) sh.rs.tred[w] = tot;
  __syncthreads();
  if (tid==0) atomicAdd(&sumsS[z*8 + (blockIdx.x & 7)], sh.rs.tred[0] + sh.rs.tred[1]);
}

// ---------- wave-parallel regularized lower incomplete gamma P(a,x) ----------
__device__ double gammainc_wave(double a, double x, double lga, int lane){
  double C = 1.0/a;
  double psum = 0.0;
  for (int b=0;b<8192;b++){
    double k = (double)(b*64 + lane + 1);
    double rr = x/(a+k);
    double pp = rr;
#pragma unroll
    for (int s=1;s<64;s<<=1){
      double t = __shfl_up(pp, s, 64);
      if (lane >= s) pp *= t;
    }
    double c = C*pp;
    psum += c;
    double clast = __shfl(c, 63, 64);
    double rlast = __shfl(rr, 63, 64);
    C = clast;
    if (rlast < 1.0 && clast*rlast/(1.0-rlast) < 1e-17) break;
  }
#pragma unroll
  for (int s=1;s<64;s<<=1) psum += __shfl_xor(psum, s, 64);
  double total = 1.0/a + psum;
  return exp(-x + a*log(x) - lga) * total;
}

// ---------- dispatch 4: centered products + tail-block finalize ----------
__global__ __launch_bounds__(256,2) void final_k(const u16* __restrict__ Xbf, const float* __restrict__ Gall,
                                                 const float* __restrict__ scal,
                                                 const double* __restrict__ rowK,
                                                 const double* __restrict__ rowL,
                                                 const double* __restrict__ sumsS,
                                                 double* __restrict__ slotbuf, u32* __restrict__ ctr,
                                                 float* __restrict__ out){
  __shared__ double red[4][3];
  __shared__ int lastFlag;
  int tid = threadIdx.x;
  int b = blockIdx.x >> 1, half = blockIdx.x & 1;
  int by,bx; bmap(b,by,bx);
  bool isdiag = (by==bx);
  int w=tid>>6, lane=tid&63, q=lane>>4, nl=lane&15;
  const bf16x8* Xb = (const bf16x8*)Xbf;
  const bf16x8* Yb = Xb + 32768;
  const float* Gx = Gall;
  const float* Gy = Gall + NPTS;
  const double inv_n = 1.0/(double)NPTS;
  double sK=0.0, sL=0.0;
#pragma unroll
  for (int k2=0;k2<8;k2++){ sK += sumsS[k2]; sL += sumsS[8+k2]; }
  double tmK = sK*(inv_n*inv_n), tmL = sL*(inv_n*inv_n);
  float negx = -1.0f/scal[0], negy = -1.0f/scal[1];
  double wgt = isdiag ? 1.0 : 2.0;
  double S1=0, S2=0, trV=0;
  int ag = by*8 + half*4 + w;
  bf16x8 axf0 = Xb[ag*128 + q*16 + nl];
  bf16x8 axf1 = Xb[ag*128 + (4+q)*16 + nl];
  bf16x8 ayf0 = Yb[ag*128 + q*16 + nl];
  bf16x8 ayf1 = Yb[ag*128 + (4+q)*16 + nl];
  int rowA = ag*16 + nl;
  float gaX = Gx[rowA], gaY = Gy[rowA];
  float gXm[4], gYm[4];
#pragma unroll
  for (int r=0;r<4;r++){ gXm[r] = __shfl(gaX, q*4+r, 64); gYm[r] = __shfl(gaY, q*4+r, 64); }
  double rmKi[4], rmLi[4];
#pragma unroll
  for (int r=0;r<4;r++){
    int i = ag*16 + q*4 + r;
    rmKi[r] = rowK[i]*inv_n; rmLi[r] = rowL[i]*inv_n;
  }
#pragma unroll
  for (int tb=0;tb<8;tb++){
    int jg = bx*8 + tb;
    f32x4 accX = (f32x4)0.0f, accY = (f32x4)0.0f;
    accX = __builtin_amdgcn_mfma_f32_16x16x32_bf16(axf0, Xb[jg*128 + q*16 + nl],     accX, 0,0,0);
    accX = __builtin_amdgcn_mfma_f32_16x16x32_bf16(axf1, Xb[jg*128 + (4+q)*16 + nl], accX, 0,0,0);
    accY = __builtin_amdgcn_mfma_f32_16x16x32_bf16(ayf0, Yb[jg*128 + q*16 + nl],     accY, 0,0,0);
    accY = __builtin_amdgcn_mfma_f32_16x16x32_bf16(ayf1, Yb[jg*128 + (4+q)*16 + nl], accY, 0,0,0);
    int j = jg*16 + nl;
    float gbX = Gx[j], gbY = Gy[j];
    double cmK = rowK[j]*inv_n - tmK;
    double cmL = rowL[j]*inv_n - tmL;
#pragma unroll
    for (int r=0;r<4;r++){
      int i = ag*16 + q*4 + r;
      float dx = (gXm[r] + gbX) - 2.0f*accX[r];
      float dy = (gYm[r] + gbY) - 2.0f*accY[r];
      bool dg = isdiag && i==j;
      if (dg){ dx = 0.f; dy = 0.f; }
      float kx = expf(dx*negx);
      float lv = expf(dy*negy);
      double kc = ((double)kx - rmKi[r]) - cmK;
      double lc = ((double)lv - rmLi[r]) - cmL;
      double prod = kc*lc;
      S1 += wgt*prod;
      double vv = (prod*prod)*(1.0/36.0);
      S2 += wgt*vv;
      if (dg) trV += vv;
    }
  }
  double vals[3]={S1,S2,trV};
#pragma unroll
  for (int v=0;v<3;v++){
    double x = vals[v];
#pragma unroll
    for (int s2=1;s2<64;s2<<=1) x += __shfl_xor(x, s2, 64);
    if (lane==0) red[w][v]=x;
  }
  __syncthreads();
  if (tid < 3){
    double val = red[0][tid]+red[1][tid]+red[2][tid]+red[3][tid];
    atomicAdd(&slotbuf[(size_t)(blockIdx.x & 15)*4 + tid], val);   // 16 slots: spreads contention
  }
  __syncthreads();                 // barrier drain (vmcnt 0) pushes wave-0's atomics to coherence point
  if (tid==0){
    __threadfence();
    u32 old = atomicAdd(ctr, 1u);
    lastFlag = (old == (u32)(2*NBLK - 1)) ? 1 : 0;
  }
  __syncthreads();
  if (!lastFlag) return;

  // ---- tail block: reduce slots + gamma-ppf ----
  if (tid >= 64) return;
  double t0=0.0, t1=0.0, t2=0.0;
  if (lane < 16){
    double* sp = slotbuf + (size_t)lane*4;
    t0 = atomicAdd(&sp[0], 0.0);   // atomic RMW read: coherent across XCD L2s
    t1 = atomicAdd(&sp[1], 0.0);
    t2 = atomicAdd(&sp[2], 0.0);
  }
#pragma unroll
  for (int s2=1;s2<64;s2<<=1){
    t0 += __shfl_xor(t0, s2, 64);
    t1 += __shfl_xor(t1, s2, 64);
    t2 += __shfl_xor(t2, s2, 64);
  }
  const double n = (double)NPTS;
  double S1t=t0, S2t=t1, trVt=t2;
  double testStat = S1t/n;
  double varHSIC = (S2t - trVt)/n/(n-1.0);
  varHSIC = varHSIC*72.0*(n-4.0)*(n-5.0)/n/(n-1.0)/(n-2.0)/(n-3.0);
  double muX = (sK-n)/n/(n-1.0);   // trace(K) = n exactly (diag forced to 1)
  double muY = (sL-n)/n/(n-1.0);
  double mHSIC = (1.0 + muX*muY - muX - muY)/n;
  double al = mHSIC*mHSIC/varHSIC;
  double bet = varHSIC*n/mHSIC;
  double p = (double)((float)(1.0-0.8));
  double lga = lgamma(al);
  double lo = 0.0, hi = al + 10.0*sqrt(al) + 100.0;
  const double zp = -0.8416212335729142957;  // Phi^-1(0.2)
  double tt = 1.0 - 1.0/(9.0*al) + zp/(3.0*sqrt(al));
  double x = al*tt*tt*tt;
  if (!(x > 0.0) || !(x < hi)) x = 0.5*hi;
  for (int it=0; it<2; ++it){
    double P = gammainc_wave(al, x, lga, lane);
    double diff = P - p;
    if (diff < 0.0) lo = x; else hi = x;
    if (fabs(diff) < 1e-12) break;
    double pdf = exp(-x + (al-1.0)*log(x) - lga);
    double nx = x - diff/pdf;
    if (!(nx > lo) || !(nx < hi)) nx = 0.5*(lo+hi);
    x = nx;
  }
  if (lane==0){
    out[0]=(float)testStat;
    out[1]=(float)(bet*x);
  }
}

// ---------- host ----------
extern "C" void kernel_launch(void* const* d_in, const int* in_sizes, int n_in,
                              void* d_out, int out_size, void* d_ws, size_t ws_size,
                              hipStream_t stream) {
  const float* X = (const float*)d_in[0];
  const float* Y = (const float*)d_in[1];
  float* out = (float*)d_out;
  char* ws = (char*)d_ws;

  double* sumsS    = (double*)ws;                    // 16 doubles (8 slots per z)
  float*  scal     = (float*)(ws + 128);             // 2 floats
  u32*    histsum  = (u32*)(ws + 256);               // 2*836 u32 = 6688 B
  double* slotbuf  = (double*)(ws + 7168);           // 16 slots x 4 doubles = 512 B
  u32*    ctr      = (u32*)(ws + 7680);              // done counter
  double* rowK     = (double*)(ws + 8192);           // 32 KB
  double* rowL     = (double*)(ws + 40960);          // 32 KB
  float*  Gall     = (float*)(ws + 73728);           // 32 KB
  u16*    Xbf      = (u16*)(ws + (4u<<20));          // 1 MB (swizzled fragment-major)
  size_t need = (size_t)(4u<<20) + (size_t)2*NPTS*DIM*2;   // ~5.2 MB

  if (ws_size < need) return;

  convert_k<<<64,256,0,stream>>>(X, Y, Xbf, Gall, histsum, rowK, rowL, sumsS, slotbuf, ctr);
  hist_k<<<dim3(NBLK,2),256,0,stream>>>(Xbf, Gall, histsum);
  rowsum_k<<<dim3(NBLK,2),256,0,stream>>>(Xbf, Gall, histsum, scal, rowK, rowL, sumsS);
  final_k<<<2*NBLK,256,0,stream>>>(Xbf, Gall, scal, rowK, rowL, sumsS, slotbuf, ctr, out);
}

// Round 4
// 145.522 us; speedup vs baseline: 3.2702x; 1.0558x over previous
//
#include <hip/hip_runtime.h>

typedef unsigned int u32;
typedef unsigned short u16;
typedef __attribute__((ext_vector_type(8))) short bf16x8;   // 8 bf16 in 4 VGPRs
typedef __attribute__((ext_vector_type(4))) float f32x4;

#define NPTS 4096
#define DIM  64
#define NB   32          // 4096/128
#define NBLK 528         // NB*(NB+1)/2 upper-tri 128x128 blocks
#define WLO16 0x4140u    // window low: float bits 0x41400000 = 12.0
#define NWBIN 832        // t16 in [0x4140, 0x4480) -> D in [12, 1024)
#define RSTR 836         // histogram stride in u32 (834 bins + pad)
// full-matrix ranks: diag(4096 zeros) + doubled upper-tri; m_ut = 8386560
#define KF1C 8390654u
#define KF2C 8390656u

// Swizzled fragment-major layout (chunk = bf16x8 = 16 B):
//   chunk_index(row, f) = (row>>4)*128 + f*16 + (row&15)

// map linear upper-tri block id -> (by,bx), bx>=by
__device__ __forceinline__ void bmap(int b, int& by, int& bx){
  by = 0;
  while (b >= NB - by){ b -= NB - by; by++; }
  bx = by + b;
}

// fp32 -> bf16 bits, round-nearest-even
__device__ __forceinline__ u16 f2bf(float x){
  u32 u = __float_as_uint(x);
  return (u16)((u + 0x7fffu + ((u>>16)&1u)) >> 16);
}

// ---------- dispatch 1: convert to swizzled bf16 + norms; zero accumulators ----------
__global__ __launch_bounds__(256) void convert_k(const float* __restrict__ X, const float* __restrict__ Y,
                                                 u16* __restrict__ Xbf, float* __restrict__ Gall,
                                                 u32* __restrict__ histsum, double* __restrict__ rowK,
                                                 double* __restrict__ rowL, double* __restrict__ sumsS,
                                                 double* __restrict__ slotbuf, u32* __restrict__ ctr){
  int t = blockIdx.x*256 + threadIdx.x;     // 16384 threads, 2 per row (half-row each)
  int rid = t >> 1, hf = t & 1;
  int z = rid >> 12, row = rid & 4095;
  const float* src = (z ? Y : X) + (size_t)row*DIM + hf*32;
  u16* basep = Xbf + ((size_t)z*32768 + (size_t)(row>>4)*128 + (row&15))*8;
  float g = 0.f;
#pragma unroll
  for (int f=0; f<4; f++){
    float4 f0 = *(const float4*)(src + f*8);
    float4 f1 = *(const float4*)(src + f*8 + 4);
    g = fmaf(f0.x,f0.x,g); g = fmaf(f0.y,f0.y,g); g = fmaf(f0.z,f0.z,g); g = fmaf(f0.w,f0.w,g);
    g = fmaf(f1.x,f1.x,g); g = fmaf(f1.y,f1.y,g); g = fmaf(f1.z,f1.z,g); g = fmaf(f1.w,f1.w,g);
    ushort4 h0, h1;
    h0.x=f2bf(f0.x); h0.y=f2bf(f0.y); h0.z=f2bf(f0.z); h0.w=f2bf(f0.w);
    h1.x=f2bf(f1.x); h1.y=f2bf(f1.y); h1.z=f2bf(f1.z); h1.w=f2bf(f1.w);
    u16* dst = basep + (size_t)(hf*4 + f)*16*8;
    *(ushort4*)dst = h0;
    *(ushort4*)(dst+4) = h1;
  }
  g += __shfl_xor(g, 1, 64);               // combine the two half-row partials
  if (hf==0) Gall[rid] = g;
  // zero atomic accumulators (workspace is re-poisoned between runs)
  if (t < NPTS){ rowK[t] = 0.0; rowL[t] = 0.0; }
  if (t < 2*RSTR) histsum[t] = 0u;
  if (t < 64) slotbuf[t] = 0.0;
  if (t < 16) sumsS[t] = 0.0;
  if (t == 0) *ctr = 0u;
}

// ---------- dispatch 2: upper-tri block histogram, LDS-staged B panel ----------
__global__ __launch_bounds__(256,2) void hist_k(const u16* __restrict__ Xbf, const float* __restrict__ Gall,
                                                u32* __restrict__ histsum){
  __shared__ u32 lh[4][RSTR];
  __shared__ bf16x8 sB[1024];               // 16 KB: B panel (8 row-groups x 128 chunks)
  int z = blockIdx.y, tid = threadIdx.x;
  int by,bx; bmap(blockIdx.x, by, bx);
  bool isdiag = (by==bx);
  u32 wgt = isdiag ? 1u : 2u;
  int w=tid>>6, lane=tid&63, q=lane>>4, nl=lane&15;
  int cp = lane & 3;                        // replica copy: splits same-bin serialization 4x
  const bf16x8* Xb = (const bf16x8*)Xbf + (size_t)z*32768;
  const bf16x8* srcB = Xb + (size_t)(bx*8)*128;
  for (int t=tid;t<1024;t+=256) sB[t] = srcB[t];
  for (int t=tid;t<4*RSTR;t+=256) ((u32*)lh)[t]=0;
  __syncthreads();
  const float* Gz = Gall + z*NPTS;
  int ag0 = by*8 + w, ag1 = by*8 + 4 + w;
  bf16x8 a0f0 = Xb[ag0*128 + q*16 + nl];
  bf16x8 a0f1 = Xb[ag0*128 + (4+q)*16 + nl];
  bf16x8 a1f0 = Xb[ag1*128 + q*16 + nl];
  bf16x8 a1f1 = Xb[ag1*128 + (4+q)*16 + nl];
  float ga0 = Gz[ag0*16 + nl], ga1 = Gz[ag1*16 + nl];
  float g0m[4], g1m[4];
#pragma unroll
  for (int r=0;r<4;r++){ g0m[r] = __shfl(ga0, q*4+r, 64); g1m[r] = __shfl(ga1, q*4+r, 64); }
#pragma unroll
  for (int tb=0;tb<8;tb++){
    bf16x8 bf0 = sB[tb*128 + q*16 + nl];
    bf16x8 bf1 = sB[tb*128 + (4+q)*16 + nl];
    f32x4 acc0 = (f32x4)0.0f, acc1 = (f32x4)0.0f;
    acc0 = __builtin_amdgcn_mfma_f32_16x16x32_bf16(a0f0, bf0, acc0, 0,0,0);
    acc0 = __builtin_amdgcn_mfma_f32_16x16x32_bf16(a0f1, bf1, acc0, 0,0,0);
    acc1 = __builtin_amdgcn_mfma_f32_16x16x32_bf16(a1f0, bf0, acc1, 0,0,0);
    acc1 = __builtin_amdgcn_mfma_f32_16x16x32_bf16(a1f1, bf1, acc1, 0,0,0);
    int j = (bx*8 + tb)*16 + nl;
    float gb = Gz[j];
#pragma unroll
    for (int r=0;r<4;r++){
      float d0 = (g0m[r] + gb) - 2.0f*acc0[r];
      float d1 = (g1m[r] + gb) - 2.0f*acc1[r];
      if (isdiag){
        if (ag0*16 + q*4 + r == j) d0 = 0.f;
        if (ag1*16 + q*4 + r == j) d1 = 0.f;
      }
      u32 t0 = __float_as_uint(d0) >> 16;
      u32 bin0 = (t0 < WLO16) ? 0u : (t0 >= WLO16+NWBIN) ? (u32)(NWBIN+1) : (t0 - WLO16 + 1u);
      atomicAdd(&lh[cp][bin0], wgt);
      u32 t1 = __float_as_uint(d1) >> 16;
      u32 bin1 = (t1 < WLO16) ? 0u : (t1 >= WLO16+NWBIN) ? (u32)(NWBIN+1) : (t1 - WLO16 + 1u);
      atomicAdd(&lh[cp][bin1], wgt);
    }
  }
  __syncthreads();
  u32* dst = histsum + (size_t)z*RSTR;
  for (int t=tid;t<RSTR;t+=256){
    u32 v = lh[0][t] + lh[1][t] + lh[2][t] + lh[3][t];
    if (v) atomicAdd(&dst[t], v);
  }
}

// ---------- dispatch 3: per-block median scan + upper-tri row sums (LDS-staged B) ----------
__global__ __launch_bounds__(256,2) void rowsum_k(const u16* __restrict__ Xbf, const float* __restrict__ Gall,
                                                  const u32* __restrict__ histsum, float* __restrict__ scal,
                                                  double* __restrict__ rowK, double* __restrict__ rowL,
                                                  double* __restrict__ sumsS){
  __shared__ union {
    struct { u32 wsum[4]; double svals[2]; float scal_sh; } sc;
    struct { double rowacc[128]; double colLDS[4][128]; double tred[2]; } rs;
  } sh;
  __shared__ bf16x8 sB[1024];               // 16 KB B panel
  int z = blockIdx.y, tid = threadIdx.x;
  int w=tid>>6, lane=tid&63, q=lane>>4, nl=lane&15;
  int by,bx; bmap(blockIdx.x, by, bx);
  bool isdiag = (by==bx);
  const bf16x8* Xb = (const bf16x8*)Xbf + (size_t)z*32768;
  const bf16x8* srcB = Xb + (size_t)(bx*8)*128;
  for (int t=tid;t<1024;t+=256) sB[t] = srcB[t];   // staging overlaps the scan prologue

  // --- scan prologue: compute median width from histsum (every block, L2 hits) ---
  {
    u32 c4[4] = {0,0,0,0};
    if (tid < 209){
      const u32* base = histsum + (size_t)z*RSTR + 4*tid;
      int lim = RSTR - 4*tid;
      c4[0] = base[0];
      if (lim>1) c4[1] = base[1];
      if (lim>2) c4[2] = base[2];
      if (lim>3) c4[3] = base[3];
    }
    u32 s = c4[0]+c4[1]+c4[2]+c4[3];
    u32 pre = s;
#pragma unroll
    for (int off=1; off<64; off<<=1){
      u32 t2 = __shfl_up(pre, off, 64);
      if (lane >= off) pre += t2;
    }
    if (lane==63) sh.sc.wsum[w] = pre;
    __syncthreads();
    u32 base2 = 0;
    for (int k=0;k<w;k++) base2 += sh.sc.wsum[k];
    u32 incl = base2 + pre, excl = incl - s;
    u32 ks[2] = {KF1C,KF2C};
#pragma unroll
    for (int w2=0; w2<2; w2++){
      if (ks[w2] >= excl && ks[w2] < incl){
        u32 acc = excl;
#pragma unroll
        for (int j=0;j<4;j++){
          if (ks[w2] < acc + c4[j]){
            int b = tid*4 + j;
            double lo, hi;
            if (b==0){ lo=12.0; hi=12.0; }
            else if (b>=NWBIN+1){ lo=1024.0; hi=1024.0; }
            else {
              u32 t16 = WLO16 + (u32)b - 1u;
              lo = (double)__uint_as_float(t16<<16);
              hi = (double)__uint_as_float((t16+1u)<<16);
            }
            double frac = ((double)(ks[w2]-acc) + 0.5)/(double)c4[j];
            sh.sc.svals[w2] = lo + (hi-lo)*frac;
            break;
          }
          acc += c4[j];
        }
      }
    }
    __syncthreads();
    if (tid==0){
      float med = (float)(0.5*(sh.sc.svals[0]+sh.sc.svals[1]));
      float wd = sqrtf(0.5f*med);
      float sc2 = 2.0f*wd*wd;
      sh.sc.scal_sh = sc2;
      if (blockIdx.x==0) scal[z] = sc2;    // for final_k
    }
    __syncthreads();
  }
  float negi = -1.0f / sh.sc.scal_sh;
  __syncthreads();                          // done reading union.sc before union.rs writes

  // --- rowsum body ---
  const float* Gz = Gall + z*NPTS;
  int ag0 = by*8 + w, ag1 = by*8 + 4 + w;
  bf16x8 a0f0 = Xb[ag0*128 + q*16 + nl];
  bf16x8 a0f1 = Xb[ag0*128 + (4+q)*16 + nl];
  bf16x8 a1f0 = Xb[ag1*128 + q*16 + nl];
  bf16x8 a1f1 = Xb[ag1*128 + (4+q)*16 + nl];
  float ga0 = Gz[ag0*16 + nl], ga1 = Gz[ag1*16 + nl];
  float g0m[4], g1m[4];
#pragma unroll
  for (int r=0;r<4;r++){ g0m[r] = __shfl(ga0, q*4+r, 64); g1m[r] = __shfl(ga1, q*4+r, 64); }
  double rs0[4] = {0,0,0,0}, rs1[4] = {0,0,0,0};
#pragma unroll
  for (int tb=0;tb<8;tb++){
    bf16x8 bf0 = sB[tb*128 + q*16 + nl];
    bf16x8 bf1 = sB[tb*128 + (4+q)*16 + nl];
    f32x4 acc0 = (f32x4)0.0f, acc1 = (f32x4)0.0f;
    acc0 = __builtin_amdgcn_mfma_f32_16x16x32_bf16(a0f0, bf0, acc0, 0,0,0);
    acc0 = __builtin_amdgcn_mfma_f32_16x16x32_bf16(a0f1, bf1, acc0, 0,0,0);
    acc1 = __builtin_amdgcn_mfma_f32_16x16x32_bf16(a1f0, bf0, acc1, 0,0,0);
    acc1 = __builtin_amdgcn_mfma_f32_16x16x32_bf16(a1f1, bf1, acc1, 0,0,0);
    int j = (bx*8 + tb)*16 + nl;
    float gb = Gz[j];
    double cs = 0.0;
#pragma unroll
    for (int r=0;r<4;r++){
      float d0 = (g0m[r] + gb) - 2.0f*acc0[r];
      float d1 = (g1m[r] + gb) - 2.0f*acc1[r];
      if (isdiag){
        if (ag0*16 + q*4 + r == j) d0 = 0.f;    // exact K_ii = 1
        if (ag1*16 + q*4 + r == j) d1 = 0.f;
      }
      double e0 = (double)expf(d0*negi);
      double e1 = (double)expf(d1*negi);
      rs0[r] += e0; rs1[r] += e1;
      cs += e0 + e1;
    }
    cs += __shfl_xor(cs, 16, 64);
    cs += __shfl_xor(cs, 32, 64);
    if (q==0) sh.rs.colLDS[w][tb*16 + nl] = cs;
  }
#pragma unroll
  for (int r=0;r<4;r++){
    double v0 = rs0[r], v1 = rs1[r];
    v0 += __shfl_xor(v0,1,64); v0 += __shfl_xor(v0,2,64);
    v0 += __shfl_xor(v0,4,64); v0 += __shfl_xor(v0,8,64);
    v1 += __shfl_xor(v1,1,64); v1 += __shfl_xor(v1,2,64);
    v1 += __shfl_xor(v1,4,64); v1 += __shfl_xor(v1,8,64);
    rs0[r] = v0; rs1[r] = v1;
  }
  if (nl==0){
#pragma unroll
    for (int r=0;r<4;r++){
      sh.rs.rowacc[w*16 + q*4 + r]     = rs0[r];
      sh.rs.rowacc[(4+w)*16 + q*4 + r] = rs1[r];
    }
  }
  __syncthreads();
  double tot = 0.0;
  if (tid < 128){
    double rv = sh.rs.rowacc[tid];
    double cv = sh.rs.colLDS[0][tid] + sh.rs.colLDS[1][tid] + sh.rs.colLDS[2][tid] + sh.rs.colLDS[3][tid];
    double* rowG = z ? rowL : rowK;
    atomicAdd(&rowG[by*128 + tid], rv);
    if (!isdiag) atomicAdd(&rowG[bx*128 + tid], cv);
    tot = rv + (isdiag ? 0.0 : cv);
  }
#pragma unroll
  for (int s2=1;s2<64;s2<<=1) tot += __shfl_xor(tot, s2, 64);
  if (lane==0 && w<2) sh.rs.tred[w] = tot;
  __syncthreads();
  if (tid==0) atomicAdd(&sumsS[z*8 + (blockIdx.x & 7)], sh.rs.tred[0] + sh.rs.tred[1]);
}

// ---------- block-parallel (256-thread) regularized lower incomplete gamma P(a,x) ----------
__device__ double gammainc_block(double a, double x, double lga,
                                 int tid, int lane, int w,
                                 double* wp /*shared[4]*/, double* bs /*shared[4]*/){
  double C = 1.0/a;
  double psum = 0.0;
  for (int b=0;b<2048;b++){
    double k = (double)(b*256 + tid + 1);
    double rr = x/(a+k);
    double pp = rr;
#pragma unroll
    for (int s=1;s<64;s<<=1){
      double t = __shfl_up(pp, s, 64);
      if (lane >= s) pp *= t;
    }
    double wtot = __shfl(pp, 63, 64);
    if (lane==0) wp[w] = wtot;
    __syncthreads();
    double cross = 1.0;
    for (int k2=0;k2<w;k2++) cross *= wp[k2];
    double call = wp[0]*wp[1]*wp[2]*wp[3];
    double c = C*cross*pp;
    psum += c;
    double Cn = C*call;
    C = Cn;
    double rlast = x/(a + (double)(b*256 + 256));
    __syncthreads();                      // wp reused next iteration
    if (rlast < 1.0 && Cn*rlast/(1.0-rlast) < 1e-17) break;
  }
#pragma unroll
  for (int s=1;s<64;s<<=1) psum += __shfl_xor(psum, s, 64);
  if (lane==0) bs[w] = psum;
  __syncthreads();
  double total = 1.0/a + bs[0]+bs[1]+bs[2]+bs[3];
  __syncthreads();
  return exp(-x + a*log(x) - lga) * total;
}

// ---------- dispatch 4: centered products (both halves/block, LDS panels) + tail finalize ----------
__global__ __launch_bounds__(256,2) void final_k(const u16* __restrict__ Xbf, const float* __restrict__ Gall,
                                                 const float* __restrict__ scal,
                                                 const double* __restrict__ rowK,
                                                 const double* __restrict__ rowL,
                                                 const double* __restrict__ sumsS,
                                                 double* __restrict__ slotbuf, u32* __restrict__ ctr,
                                                 float* __restrict__ out){
  __shared__ bf16x8 sBX[1024];              // 16 KB: X B-panel
  __shared__ bf16x8 sBY[1024];              // 16 KB: Y B-panel
  __shared__ double red[4][3];
  __shared__ double gwp[4], gbs[4], stot[3];
  __shared__ int lastFlag;
  int tid = threadIdx.x;
  int by,bx; bmap(blockIdx.x,by,bx);
  bool isdiag = (by==bx);
  int w=tid>>6, lane=tid&63, q=lane>>4, nl=lane&15;
  const bf16x8* Xb = (const bf16x8*)Xbf;
  const bf16x8* Yb = Xb + 32768;
  const bf16x8* srcBX = Xb + (size_t)(bx*8)*128;
  const bf16x8* srcBY = Yb + (size_t)(bx*8)*128;
  for (int t=tid;t<1024;t+=256){ sBX[t] = srcBX[t]; sBY[t] = srcBY[t]; }
  const float* Gx = Gall;
  const float* Gy = Gall + NPTS;
  const double inv_n = 1.0/(double)NPTS;
  double sK=0.0, sL=0.0;
#pragma unroll
  for (int k2=0;k2<8;k2++){ sK += sumsS[k2]; sL += sumsS[8+k2]; }
  double tmK = sK*(inv_n*inv_n), tmL = sL*(inv_n*inv_n);
  float negx = -1.0f/scal[0], negy = -1.0f/scal[1];
  double wgt = isdiag ? 1.0 : 2.0;
  double S1=0, S2=0, trV=0;
  // A fragments for BOTH halves (row groups by*8 + 0..7)
  int agA = by*8 + w;                       // half 0
  int agB = by*8 + 4 + w;                   // half 1
  bf16x8 axf0A = Xb[agA*128 + q*16 + nl];
  bf16x8 axf1A = Xb[agA*128 + (4+q)*16 + nl];
  bf16x8 ayf0A = Yb[agA*128 + q*16 + nl];
  bf16x8 ayf1A = Yb[agA*128 + (4+q)*16 + nl];
  bf16x8 axf0B = Xb[agB*128 + q*16 + nl];
  bf16x8 axf1B = Xb[agB*128 + (4+q)*16 + nl];
  bf16x8 ayf0B = Yb[agB*128 + q*16 + nl];
  bf16x8 ayf1B = Yb[agB*128 + (4+q)*16 + nl];
  float gaXA = Gx[agA*16 + nl], gaYA = Gy[agA*16 + nl];
  float gaXB = Gx[agB*16 + nl], gaYB = Gy[agB*16 + nl];
  float gXmA[4], gYmA[4], gXmB[4], gYmB[4];
#pragma unroll
  for (int r=0;r<4;r++){
    gXmA[r] = __shfl(gaXA, q*4+r, 64); gYmA[r] = __shfl(gaYA, q*4+r, 64);
    gXmB[r] = __shfl(gaXB, q*4+r, 64); gYmB[r] = __shfl(gaYB, q*4+r, 64);
  }
  double rmKiA[4], rmLiA[4], rmKiB[4], rmLiB[4];
#pragma unroll
  for (int r=0;r<4;r++){
    int iA = agA*16 + q*4 + r, iB = agB*16 + q*4 + r;
    rmKiA[r] = rowK[iA]*inv_n; rmLiA[r] = rowL[iA]*inv_n;
    rmKiB[r] = rowK[iB]*inv_n; rmLiB[r] = rowL[iB]*inv_n;
  }
  __syncthreads();                          // panels staged
#pragma unroll
  for (int tb=0;tb<8;tb++){
    bf16x8 bx0 = sBX[tb*128 + q*16 + nl];
    bf16x8 bx1 = sBX[tb*128 + (4+q)*16 + nl];
    bf16x8 by0 = sBY[tb*128 + q*16 + nl];
    bf16x8 by1 = sBY[tb*128 + (4+q)*16 + nl];
    f32x4 aXA = (f32x4)0.0f, aYA = (f32x4)0.0f, aXB = (f32x4)0.0f, aYB = (f32x4)0.0f;
    aXA = __builtin_amdgcn_mfma_f32_16x16x32_bf16(axf0A, bx0, aXA, 0,0,0);
    aXA = __builtin_amdgcn_mfma_f32_16x16x32_bf16(axf1A, bx1, aXA, 0,0,0);
    aYA = __builtin_amdgcn_mfma_f32_16x16x32_bf16(ayf0A, by0, aYA, 0,0,0);
    aYA = __builtin_amdgcn_mfma_f32_16x16x32_bf16(ayf1A, by1, aYA, 0,0,0);
    aXB = __builtin_amdgcn_mfma_f32_16x16x32_bf16(axf0B, bx0, aXB, 0,0,0);
    aXB = __builtin_amdgcn_mfma_f32_16x16x32_bf16(axf1B, bx1, aXB, 0,0,0);
    aYB = __builtin_amdgcn_mfma_f32_16x16x32_bf16(ayf0B, by0, aYB, 0,0,0);
    aYB = __builtin_amdgcn_mfma_f32_16x16x32_bf16(ayf1B, by1, aYB, 0,0,0);
    int j = (bx*8 + tb)*16 + nl;
    float gbX = Gx[j], gbY = Gy[j];
    double cmK = rowK[j]*inv_n - tmK;
    double cmL = rowL[j]*inv_n - tmL;
#pragma unroll
    for (int r=0;r<4;r++){
      int iA = agA*16 + q*4 + r;
      float dxA = (gXmA[r] + gbX) - 2.0f*aXA[r];
      float dyA = (gYmA[r] + gbY) - 2.0f*aYA[r];
      bool dgA = isdiag && iA==j;
      if (dgA){ dxA = 0.f; dyA = 0.f; }
      float kxA = expf(dxA*negx);
      float lvA = expf(dyA*negy);
      double kcA = ((double)kxA - rmKiA[r]) - cmK;
      double lcA = ((double)lvA - rmLiA[r]) - cmL;
      double prodA = kcA*lcA;
      S1 += wgt*prodA;
      double vvA = (prodA*prodA)*(1.0/36.0);
      S2 += wgt*vvA;
      if (dgA) trV += vvA;

      int iB = agB*16 + q*4 + r;
      float dxB = (gXmB[r] + gbX) - 2.0f*aXB[r];
      float dyB = (gYmB[r] + gbY) - 2.0f*aYB[r];
      bool dgB = isdiag && iB==j;
      if (dgB){ dxB = 0.f; dyB = 0.f; }
      float kxB = expf(dxB*negx);
      float lvB = expf(dyB*negy);
      double kcB = ((double)kxB - rmKiB[r]) - cmK;
      double lcB = ((double)lvB - rmLiB[r]) - cmL;
      double prodB = kcB*lcB;
      S1 += wgt*prodB;
      double vvB = (prodB*prodB)*(1.0/36.0);
      S2 += wgt*vvB;
      if (dgB) trV += vvB;
    }
  }
  double vals[3]={S1,S2,trV};
#pragma unroll
  for (int v=0;v<3;v++){
    double x = vals[v];
#pragma unroll
    for (int s2=1;s2<64;s2<<=1) x += __shfl_xor(x, s2, 64);
    if (lane==0) red[w][v]=x;
  }
  __syncthreads();
  if (tid < 3){
    double val = red[0][tid]+red[1][tid]+red[2][tid]+red[3][tid];
    // returning atomic: completion (not just issue) is guaranteed before vmcnt drains
    double old = atomicAdd(&slotbuf[(size_t)(blockIdx.x & 15)*4 + tid], val);
    asm volatile("" :: "v"(old));          // keep the return value live
  }
  __syncthreads();                          // drains vmcnt: slot adds complete before ctr bump
  if (tid==0){
    u32 old = atomicAdd(ctr, 1u);
    lastFlag = (old == (u32)(NBLK - 1)) ? 1 : 0;
  }
  __syncthreads();
  if (!lastFlag) return;

  // ---- tail block (all 256 threads): reduce slots + gamma-ppf ----
  if (w==0){
    double t0=0.0, t1=0.0, t2=0.0;
    if (lane < 16){
      double* sp = slotbuf + (size_t)lane*4;
      t0 = atomicAdd(&sp[0], 0.0);   // atomic RMW read: coherent across XCD L2s
      t1 = atomicAdd(&sp[1], 0.0);
      t2 = atomicAdd(&sp[2], 0.0);
    }
#pragma unroll
    for (int s2=1;s2<16;s2<<=1){
      t0 += __shfl_xor(t0, s2, 64);
      t1 += __shfl_xor(t1, s2, 64);
      t2 += __shfl_xor(t2, s2, 64);
    }
    if (lane==0){ stot[0]=t0; stot[1]=t1; stot[2]=t2; }
  }
  __syncthreads();
  const double n = (double)NPTS;
  double S1t=stot[0], S2t=stot[1], trVt=stot[2];
  double testStat = S1t/n;
  double varHSIC = (S2t - trVt)/n/(n-1.0);
  varHSIC = varHSIC*72.0*(n-4.0)*(n-5.0)/n/(n-1.0)/(n-2.0)/(n-3.0);
  double muX = (sK-n)/n/(n-1.0);   // trace(K) = n exactly (diag forced to 1)
  double muY = (sL-n)/n/(n-1.0);
  double mHSIC = (1.0 + muX*muY - muX - muY)/n;
  double al = mHSIC*mHSIC/varHSIC;
  double bet = varHSIC*n/mHSIC;
  double p = (double)((float)(1.0-0.8));
  double lga = lgamma(al);
  double lo = 0.0, hi = al + 10.0*sqrt(al) + 100.0;
  const double zp = -0.8416212335729142957;  // Phi^-1(0.2)
  double tt = 1.0 - 1.0/(9.0*al) + zp/(3.0*sqrt(al));
  double x = al*tt*tt*tt;
  if (!(x > 0.0) || !(x < hi)) x = 0.5*hi;
  for (int it=0; it<2; ++it){
    double P = gammainc_block(al, x, lga, tid, lane, w, gwp, gbs);
    double diff = P - p;
    if (diff < 0.0) lo = x; else hi = x;
    if (fabs(diff) < 1e-12) break;
    double pdf = exp(-x + (al-1.0)*log(x) - lga);
    double nx = x - diff/pdf;
    if (!(nx > lo) || !(nx < hi)) nx = 0.5*(lo+hi);
    x = nx;
  }
  if (tid==0){
    out[0]=(float)testStat;
    out[1]=(float)(bet*x);
  }
}

// ---------- host ----------
extern "C" void kernel_launch(void* const* d_in, const int* in_sizes, int n_in,
                              void* d_out, int out_size, void* d_ws, size_t ws_size,
                              hipStream_t stream) {
  const float* X = (const float*)d_in[0];
  const float* Y = (const float*)d_in[1];
  float* out = (float*)d_out;
  char* ws = (char*)d_ws;

  double* sumsS    = (double*)ws;                    // 16 doubles (8 slots per z)
  float*  scal     = (float*)(ws + 128);             // 2 floats
  u32*    histsum  = (u32*)(ws + 256);               // 2*836 u32 = 6688 B
  double* slotbuf  = (double*)(ws + 7168);           // 16 slots x 4 doubles = 512 B
  u32*    ctr      = (u32*)(ws + 7680);              // done counter
  double* rowK     = (double*)(ws + 8192);           // 32 KB
  double* rowL     = (double*)(ws + 40960);          // 32 KB
  float*  Gall     = (float*)(ws + 73728);           // 32 KB
  u16*    Xbf      = (u16*)(ws + (4u<<20));          // 1 MB (swizzled fragment-major)
  size_t need = (size_t)(4u<<20) + (size_t)2*NPTS*DIM*2;   // ~5.2 MB

  if (ws_size < need) return;

  convert_k<<<64,256,0,stream>>>(X, Y, Xbf, Gall, histsum, rowK, rowL, sumsS, slotbuf, ctr);
  hist_k<<<dim3(NBLK,2),256,0,stream>>>(Xbf, Gall, histsum);
  rowsum_k<<<dim3(NBLK,2),256,0,stream>>>(Xbf, Gall, histsum, scal, rowK, rowL, sumsS);
  final_k<<<NBLK,256,0,stream>>>(Xbf, Gall, scal, rowK, rowL, sumsS, slotbuf, ctr, out);
}

// Round 5
// 144.576 us; speedup vs baseline: 3.2916x; 1.0065x over previous
//
#include <hip/hip_runtime.h>

typedef unsigned int u32;
typedef unsigned short u16;
typedef __attribute__((ext_vector_type(8))) short bf16x8;   // 8 bf16 in 4 VGPRs
typedef __attribute__((ext_vector_type(4))) float f32x4;

#define NPTS 4096
#define DIM  64
#define NB   32          // 4096/128
#define NBLK 528         // NB*(NB+1)/2 upper-tri 128x128 blocks
#define WLO16 0x4140u    // window low: float bits 0x41400000 = 12.0
#define NWBIN 832        // t16 in [0x4140, 0x4480) -> D in [12, 1024)
#define RSTR 836         // histogram stride in u32 (834 bins + pad)
#define LOG2E 1.4426950408889634f
// full-matrix ranks: diag(4096 zeros) + doubled upper-tri; m_ut = 8386560
#define KF1C 8390654u
#define KF2C 8390656u

// Swizzled fragment-major layout (chunk = bf16x8 = 16 B):
//   chunk_index(row, f) = (row>>4)*128 + f*16 + (row&15)

// map linear upper-tri block id -> (by,bx), bx>=by
__device__ __forceinline__ void bmap(int b, int& by, int& bx){
  by = 0;
  while (b >= NB - by){ b -= NB - by; by++; }
  bx = by + b;
}

// fp32 -> bf16 bits, round-nearest-even
__device__ __forceinline__ u16 f2bf(float x){
  u32 u = __float_as_uint(x);
  return (u16)((u + 0x7fffu + ((u>>16)&1u)) >> 16);
}

// ---------- dispatch 1: convert to swizzled bf16 + norms; zero accumulators ----------
__global__ __launch_bounds__(256) void convert_k(const float* __restrict__ X, const float* __restrict__ Y,
                                                 u16* __restrict__ Xbf, float* __restrict__ Gall,
                                                 u32* __restrict__ histsum, double* __restrict__ rowK,
                                                 double* __restrict__ rowL, double* __restrict__ sumsS,
                                                 double* __restrict__ slotbuf, u32* __restrict__ ctr){
  int t = blockIdx.x*256 + threadIdx.x;     // 16384 threads, 2 per row (half-row each)
  int rid = t >> 1, hf = t & 1;
  int z = rid >> 12, row = rid & 4095;
  const float* src = (z ? Y : X) + (size_t)row*DIM + hf*32;
  u16* basep = Xbf + ((size_t)z*32768 + (size_t)(row>>4)*128 + (row&15))*8;
  float g = 0.f;
#pragma unroll
  for (int f=0; f<4; f++){
    float4 f0 = *(const float4*)(src + f*8);
    float4 f1 = *(const float4*)(src + f*8 + 4);
    g = fmaf(f0.x,f0.x,g); g = fmaf(f0.y,f0.y,g); g = fmaf(f0.z,f0.z,g); g = fmaf(f0.w,f0.w,g);
    g = fmaf(f1.x,f1.x,g); g = fmaf(f1.y,f1.y,g); g = fmaf(f1.z,f1.z,g); g = fmaf(f1.w,f1.w,g);
    ushort4 h0, h1;
    h0.x=f2bf(f0.x); h0.y=f2bf(f0.y); h0.z=f2bf(f0.z); h0.w=f2bf(f0.w);
    h1.x=f2bf(f1.x); h1.y=f2bf(f1.y); h1.z=f2bf(f1.z); h1.w=f2bf(f1.w);
    u16* dst = basep + (size_t)(hf*4 + f)*16*8;
    *(ushort4*)dst = h0;
    *(ushort4*)(dst+4) = h1;
  }
  g += __shfl_xor(g, 1, 64);               // combine the two half-row partials
  if (hf==0) Gall[rid] = g;
  // zero atomic accumulators (workspace is re-poisoned between runs)
  if (t < NPTS){ rowK[t] = 0.0; rowL[t] = 0.0; }
  if (t < 2*RSTR) histsum[t] = 0u;
  if (t < 64) slotbuf[t] = 0.0;
  if (t < 16) sumsS[t] = 0.0;
  if (t == 0) *ctr = 0u;
}

// ---------- dispatch 2: upper-tri block histogram, LDS-staged B panel ----------
__global__ __launch_bounds__(256,4) void hist_k(const u16* __restrict__ Xbf, const float* __restrict__ Gall,
                                                u32* __restrict__ histsum){
  __shared__ u32 lh[4][RSTR];
  __shared__ bf16x8 sB[1024];               // 16 KB: B panel (8 row-groups x 128 chunks)
  int z = blockIdx.y, tid = threadIdx.x;
  int by,bx; bmap(blockIdx.x, by, bx);
  bool isdiag = (by==bx);
  u32 wgt = isdiag ? 1u : 2u;
  int w=tid>>6, lane=tid&63, q=lane>>4, nl=lane&15;
  int cp = lane & 3;                        // replica copy: splits same-bin serialization 4x
  const bf16x8* Xb = (const bf16x8*)Xbf + (size_t)z*32768;
  const bf16x8* srcB = Xb + (size_t)(bx*8)*128;
  for (int t=tid;t<1024;t+=256) sB[t] = srcB[t];
  for (int t=tid;t<4*RSTR;t+=256) ((u32*)lh)[t]=0;
  __syncthreads();
  const float* Gz = Gall + z*NPTS;
  int ag0 = by*8 + w, ag1 = by*8 + 4 + w;
  bf16x8 a0f0 = Xb[ag0*128 + q*16 + nl];
  bf16x8 a0f1 = Xb[ag0*128 + (4+q)*16 + nl];
  bf16x8 a1f0 = Xb[ag1*128 + q*16 + nl];
  bf16x8 a1f1 = Xb[ag1*128 + (4+q)*16 + nl];
  float ga0 = Gz[ag0*16 + nl], ga1 = Gz[ag1*16 + nl];
  float g0m[4], g1m[4];
#pragma unroll
  for (int r=0;r<4;r++){ g0m[r] = __shfl(ga0, q*4+r, 64); g1m[r] = __shfl(ga1, q*4+r, 64); }
#pragma unroll
  for (int tb=0;tb<8;tb++){
    bf16x8 bf0 = sB[tb*128 + q*16 + nl];
    bf16x8 bf1 = sB[tb*128 + (4+q)*16 + nl];
    f32x4 acc0 = (f32x4)0.0f, acc1 = (f32x4)0.0f;
    acc0 = __builtin_amdgcn_mfma_f32_16x16x32_bf16(a0f0, bf0, acc0, 0,0,0);
    acc0 = __builtin_amdgcn_mfma_f32_16x16x32_bf16(a0f1, bf1, acc0, 0,0,0);
    acc1 = __builtin_amdgcn_mfma_f32_16x16x32_bf16(a1f0, bf0, acc1, 0,0,0);
    acc1 = __builtin_amdgcn_mfma_f32_16x16x32_bf16(a1f1, bf1, acc1, 0,0,0);
    int j = (bx*8 + tb)*16 + nl;
    float gb = Gz[j];
#pragma unroll
    for (int r=0;r<4;r++){
      float d0 = (g0m[r] + gb) - 2.0f*acc0[r];
      float d1 = (g1m[r] + gb) - 2.0f*acc1[r];
      if (isdiag){
        if (ag0*16 + q*4 + r == j) d0 = 0.f;
        if (ag1*16 + q*4 + r == j) d1 = 0.f;
      }
      u32 t0 = __float_as_uint(d0) >> 16;
      u32 bin0 = (t0 < WLO16) ? 0u : (t0 >= WLO16+NWBIN) ? (u32)(NWBIN+1) : (t0 - WLO16 + 1u);
      atomicAdd(&lh[cp][bin0], wgt);
      u32 t1 = __float_as_uint(d1) >> 16;
      u32 bin1 = (t1 < WLO16) ? 0u : (t1 >= WLO16+NWBIN) ? (u32)(NWBIN+1) : (t1 - WLO16 + 1u);
      atomicAdd(&lh[cp][bin1], wgt);
    }
  }
  __syncthreads();
  u32* dst = histsum + (size_t)z*RSTR;
  for (int t=tid;t<RSTR;t+=256){
    u32 v = lh[0][t] + lh[1][t] + lh[2][t] + lh[3][t];
    if (v) atomicAdd(&dst[t], v);
  }
}

// ---------- dispatch 3: per-block median scan + upper-tri row sums (LDS-staged B) ----------
__global__ __launch_bounds__(256,4) void rowsum_k(const u16* __restrict__ Xbf, const float* __restrict__ Gall,
                                                  const u32* __restrict__ histsum, float* __restrict__ scal,
                                                  double* __restrict__ rowK, double* __restrict__ rowL,
                                                  double* __restrict__ sumsS){
  __shared__ union {
    struct { u32 wsum[4]; double svals[2]; float scal_sh; } sc;
    struct { double rowacc[128]; double colLDS[4][128]; double tred[2]; } rs;
  } sh;
  __shared__ bf16x8 sB[1024];               // 16 KB B panel
  int z = blockIdx.y, tid = threadIdx.x;
  int w=tid>>6, lane=tid&63, q=lane>>4, nl=lane&15;
  int by,bx; bmap(blockIdx.x, by, bx);
  bool isdiag = (by==bx);
  const bf16x8* Xb = (const bf16x8*)Xbf + (size_t)z*32768;
  const bf16x8* srcB = Xb + (size_t)(bx*8)*128;
  for (int t=tid;t<1024;t+=256) sB[t] = srcB[t];   // staging overlaps the scan prologue

  // --- scan prologue: compute median width from histsum (every block, L2 hits) ---
  {
    u32 c4[4] = {0,0,0,0};
    if (tid < 209){
      const u32* base = histsum + (size_t)z*RSTR + 4*tid;
      int lim = RSTR - 4*tid;
      c4[0] = base[0];
      if (lim>1) c4[1] = base[1];
      if (lim>2) c4[2] = base[2];
      if (lim>3) c4[3] = base[3];
    }
    u32 s = c4[0]+c4[1]+c4[2]+c4[3];
    u32 pre = s;
#pragma unroll
    for (int off=1; off<64; off<<=1){
      u32 t2 = __shfl_up(pre, off, 64);
      if (lane >= off) pre += t2;
    }
    if (lane==63) sh.sc.wsum[w] = pre;
    __syncthreads();
    u32 base2 = 0;
    for (int k=0;k<w;k++) base2 += sh.sc.wsum[k];
    u32 incl = base2 + pre, excl = incl - s;
    u32 ks[2] = {KF1C,KF2C};
#pragma unroll
    for (int w2=0; w2<2; w2++){
      if (ks[w2] >= excl && ks[w2] < incl){
        u32 acc = excl;
#pragma unroll
        for (int j=0;j<4;j++){
          if (ks[w2] < acc + c4[j]){
            int b = tid*4 + j;
            double lo, hi;
            if (b==0){ lo=12.0; hi=12.0; }
            else if (b>=NWBIN+1){ lo=1024.0; hi=1024.0; }
            else {
              u32 t16 = WLO16 + (u32)b - 1u;
              lo = (double)__uint_as_float(t16<<16);
              hi = (double)__uint_as_float((t16+1u)<<16);
            }
            double frac = ((double)(ks[w2]-acc) + 0.5)/(double)c4[j];
            sh.sc.svals[w2] = lo + (hi-lo)*frac;
            break;
          }
          acc += c4[j];
        }
      }
    }
    __syncthreads();
    if (tid==0){
      float med = (float)(0.5*(sh.sc.svals[0]+sh.sc.svals[1]));
      float wd = sqrtf(0.5f*med);
      float sc2 = 2.0f*wd*wd;
      sh.sc.scal_sh = sc2;
      if (blockIdx.x==0) scal[z] = sc2;    // for final_k
    }
    __syncthreads();
  }
  float negi = -LOG2E / sh.sc.scal_sh;      // exp(x) = exp2(x*log2e): fold into scale
  __syncthreads();                          // done reading union.sc before union.rs writes

  // --- rowsum body ---
  const float* Gz = Gall + z*NPTS;
  int ag0 = by*8 + w, ag1 = by*8 + 4 + w;
  bf16x8 a0f0 = Xb[ag0*128 + q*16 + nl];
  bf16x8 a0f1 = Xb[ag0*128 + (4+q)*16 + nl];
  bf16x8 a1f0 = Xb[ag1*128 + q*16 + nl];
  bf16x8 a1f1 = Xb[ag1*128 + (4+q)*16 + nl];
  float ga0 = Gz[ag0*16 + nl], ga1 = Gz[ag1*16 + nl];
  float g0m[4], g1m[4];
#pragma unroll
  for (int r=0;r<4;r++){ g0m[r] = __shfl(ga0, q*4+r, 64); g1m[r] = __shfl(ga1, q*4+r, 64); }
  double rs0[4] = {0,0,0,0}, rs1[4] = {0,0,0,0};
#pragma unroll
  for (int tb=0;tb<8;tb++){
    bf16x8 bf0 = sB[tb*128 + q*16 + nl];
    bf16x8 bf1 = sB[tb*128 + (4+q)*16 + nl];
    f32x4 acc0 = (f32x4)0.0f, acc1 = (f32x4)0.0f;
    acc0 = __builtin_amdgcn_mfma_f32_16x16x32_bf16(a0f0, bf0, acc0, 0,0,0);
    acc0 = __builtin_amdgcn_mfma_f32_16x16x32_bf16(a0f1, bf1, acc0, 0,0,0);
    acc1 = __builtin_amdgcn_mfma_f32_16x16x32_bf16(a1f0, bf0, acc1, 0,0,0);
    acc1 = __builtin_amdgcn_mfma_f32_16x16x32_bf16(a1f1, bf1, acc1, 0,0,0);
    int j = (bx*8 + tb)*16 + nl;
    float gb = Gz[j];
    double cs = 0.0;
#pragma unroll
    for (int r=0;r<4;r++){
      float d0 = (g0m[r] + gb) - 2.0f*acc0[r];
      float d1 = (g1m[r] + gb) - 2.0f*acc1[r];
      if (isdiag){
        if (ag0*16 + q*4 + r == j) d0 = 0.f;    // exact K_ii = 1
        if (ag1*16 + q*4 + r == j) d1 = 0.f;
      }
      double e0 = (double)exp2f(d0*negi);
      double e1 = (double)exp2f(d1*negi);
      rs0[r] += e0; rs1[r] += e1;
      cs += e0 + e1;
    }
    cs += __shfl_xor(cs, 16, 64);
    cs += __shfl_xor(cs, 32, 64);
    if (q==0) sh.rs.colLDS[w][tb*16 + nl] = cs;
  }
#pragma unroll
  for (int r=0;r<4;r++){
    double v0 = rs0[r], v1 = rs1[r];
    v0 += __shfl_xor(v0,1,64); v0 += __shfl_xor(v0,2,64);
    v0 += __shfl_xor(v0,4,64); v0 += __shfl_xor(v0,8,64);
    v1 += __shfl_xor(v1,1,64); v1 += __shfl_xor(v1,2,64);
    v1 += __shfl_xor(v1,4,64); v1 += __shfl_xor(v1,8,64);
    rs0[r] = v0; rs1[r] = v1;
  }
  if (nl==0){
#pragma unroll
    for (int r=0;r<4;r++){
      sh.rs.rowacc[w*16 + q*4 + r]     = rs0[r];
      sh.rs.rowacc[(4+w)*16 + q*4 + r] = rs1[r];
    }
  }
  __syncthreads();
  double tot = 0.0;
  if (tid < 128){
    double rv = sh.rs.rowacc[tid];
    double cv = sh.rs.colLDS[0][tid] + sh.rs.colLDS[1][tid] + sh.rs.colLDS[2][tid] + sh.rs.colLDS[3][tid];
    double* rowG = z ? rowL : rowK;
    atomicAdd(&rowG[by*128 + tid], rv);
    if (!isdiag) atomicAdd(&rowG[bx*128 + tid], cv);
    tot = rv + (isdiag ? 0.0 : cv);
  }
#pragma unroll
  for (int s2=1;s2<64;s2<<=1) tot += __shfl_xor(tot, s2, 64);
  if (lane==0 && w<2) sh.rs.tred[w] = tot;
  __syncthreads();
  if (tid==0) atomicAdd(&sumsS[z*8 + (blockIdx.x & 7)], sh.rs.tred[0] + sh.rs.tred[1]);
}

// ---------- block-parallel gamma series: 1024 terms/batch (4 per thread) ----------
__device__ double gammainc_block4(double a, double x, double lga,
                                  int tid, int lane, int w,
                                  double* wp /*shared[4]*/, double* bs /*shared[4]*/){
  double C = 1.0/a;
  double psum = 0.0;
  for (int b=0;b<512;b++){
    double k0 = (double)(b*1024 + tid*4);
    double r1 = x/(a+k0+1.0), r2 = x/(a+k0+2.0), r3 = x/(a+k0+3.0), r4 = x/(a+k0+4.0);
    double p12 = r1*r2;
    double pl = p12*(r3*r4);              // product of this thread's 4 ratios
    double pp = pl;                        // inclusive prefix across 64 lanes
#pragma unroll
    for (int s=1;s<64;s<<=1){
      double t = __shfl_up(pp, s, 64);
      if (lane >= s) pp *= t;
    }
    if (lane==63) wp[w] = pp;
    __syncthreads();
    double cross = 1.0;
    for (int k2=0;k2<w;k2++) cross *= wp[k2];
    double call = wp[0]*wp[1]*wp[2]*wp[3];
    double excl = __shfl_up(pp, 1, 64);
    if (lane==0) excl = 1.0;
    double base = C*cross*excl;            // prefix before this thread's 4 terms
    double t1 = base*r1, t2 = base*p12, t3 = t2*r3, t4 = base*pl;
    psum += (t1+t2)+(t3+t4);
    double Cn = C*call;
    C = Cn;
    double rlast = x/(a + (double)(b*1024 + 1024));
    __syncthreads();                       // wp reused next iteration
    if (rlast < 1.0 && Cn*rlast/(1.0-rlast) < 1e-17) break;
  }
#pragma unroll
  for (int s=1;s<64;s<<=1) psum += __shfl_xor(psum, s, 64);
  if (lane==0) bs[w] = psum;
  __syncthreads();
  double total = 1.0/a + bs[0]+bs[1]+bs[2]+bs[3];
  __syncthreads();
  return exp(-x + a*log(x) - lga) * total;
}

// ---------- dispatch 4: centered products (1056 half-tile blocks, LDS panels) + tail finalize ----------
__global__ __launch_bounds__(256,4) void final_k(const u16* __restrict__ Xbf, const float* __restrict__ Gall,
                                                 const float* __restrict__ scal,
                                                 const double* __restrict__ rowK,
                                                 const double* __restrict__ rowL,
                                                 const double* __restrict__ sumsS,
                                                 double* __restrict__ slotbuf, u32* __restrict__ ctr,
                                                 float* __restrict__ out){
  __shared__ bf16x8 sBX[1024];              // 16 KB: X B-panel
  __shared__ bf16x8 sBY[1024];              // 16 KB: Y B-panel
  __shared__ double red[4][3];
  __shared__ double gwp[4], gbs[4], stot[3];
  __shared__ int lastFlag;
  int tid = threadIdx.x;
  int b = blockIdx.x >> 1, half = blockIdx.x & 1;
  int by,bx; bmap(b,by,bx);
  bool isdiag = (by==bx);
  int w=tid>>6, lane=tid&63, q=lane>>4, nl=lane&15;
  const bf16x8* Xb = (const bf16x8*)Xbf;
  const bf16x8* Yb = Xb + 32768;
  const bf16x8* srcBX = Xb + (size_t)(bx*8)*128;
  const bf16x8* srcBY = Yb + (size_t)(bx*8)*128;
  for (int t=tid;t<1024;t+=256){ sBX[t] = srcBX[t]; sBY[t] = srcBY[t]; }
  const float* Gx = Gall;
  const float* Gy = Gall + NPTS;
  const double inv_n = 1.0/(double)NPTS;
  double sK=0.0, sL=0.0;
#pragma unroll
  for (int k2=0;k2<8;k2++){ sK += sumsS[k2]; sL += sumsS[8+k2]; }
  double tmK = sK*(inv_n*inv_n), tmL = sL*(inv_n*inv_n);
  float negx = -LOG2E/scal[0], negy = -LOG2E/scal[1];   // exp2-folded
  double S1=0, S2=0, trV=0;                // raw sums; wgt & 1/36 hoisted to reduction
  int ag = by*8 + half*4 + w;              // this block's 4 A row-groups
  bf16x8 axf0 = Xb[ag*128 + q*16 + nl];
  bf16x8 axf1 = Xb[ag*128 + (4+q)*16 + nl];
  bf16x8 ayf0 = Yb[ag*128 + q*16 + nl];
  bf16x8 ayf1 = Yb[ag*128 + (4+q)*16 + nl];
  float gaX = Gx[ag*16 + nl], gaY = Gy[ag*16 + nl];
  float gXm[4], gYm[4];
#pragma unroll
  for (int r=0;r<4;r++){ gXm[r] = __shfl(gaX, q*4+r, 64); gYm[r] = __shfl(gaY, q*4+r, 64); }
  double rmKi[4], rmLi[4];
#pragma unroll
  for (int r=0;r<4;r++){
    int i = ag*16 + q*4 + r;
    rmKi[r] = rowK[i]*inv_n; rmLi[r] = rowL[i]*inv_n;
  }
  __syncthreads();                          // panels staged
#pragma unroll
  for (int tb=0;tb<8;tb++){
    bf16x8 bx0 = sBX[tb*128 + q*16 + nl];
    bf16x8 bx1 = sBX[tb*128 + (4+q)*16 + nl];
    bf16x8 by0 = sBY[tb*128 + q*16 + nl];
    bf16x8 by1 = sBY[tb*128 + (4+q)*16 + nl];
    f32x4 accX = (f32x4)0.0f, accY = (f32x4)0.0f;
    accX = __builtin_amdgcn_mfma_f32_16x16x32_bf16(axf0, bx0, accX, 0,0,0);
    accX = __builtin_amdgcn_mfma_f32_16x16x32_bf16(axf1, bx1, accX, 0,0,0);
    accY = __builtin_amdgcn_mfma_f32_16x16x32_bf16(ayf0, by0, accY, 0,0,0);
    accY = __builtin_amdgcn_mfma_f32_16x16x32_bf16(ayf1, by1, accY, 0,0,0);
    int j = (bx*8 + tb)*16 + nl;
    float gbX = Gx[j], gbY = Gy[j];
    double cmK = rowK[j]*inv_n - tmK;
    double cmL = rowL[j]*inv_n - tmL;
#pragma unroll
    for (int r=0;r<4;r++){
      int i = ag*16 + q*4 + r;
      float dx = (gXm[r] + gbX) - 2.0f*accX[r];
      float dy = (gYm[r] + gbY) - 2.0f*accY[r];
      bool dg = isdiag && i==j;
      if (dg){ dx = 0.f; dy = 0.f; }
      float kx = exp2f(dx*negx);
      float lv = exp2f(dy*negy);
      double kc = ((double)kx - rmKi[r]) - cmK;
      double lc = ((double)lv - rmLi[r]) - cmL;
      double prod = kc*lc;
      S1 += prod;
      S2 = fma(prod, prod, S2);
      if (dg) trV = fma(prod, prod, trV);
    }
  }
  {
    double wgt = isdiag ? 1.0 : 2.0;
    S1 *= wgt;
    S2 *= wgt*(1.0/36.0);
    trV *= (1.0/36.0);
  }
  double vals[3]={S1,S2,trV};
#pragma unroll
  for (int v=0;v<3;v++){
    double x = vals[v];
#pragma unroll
    for (int s2=1;s2<64;s2<<=1) x += __shfl_xor(x, s2, 64);
    if (lane==0) red[w][v]=x;
  }
  __syncthreads();
  if (tid < 3){
    double val = red[0][tid]+red[1][tid]+red[2][tid]+red[3][tid];
    // returning atomic: completion (not just issue) before the barrier's vmcnt drain
    double old = atomicAdd(&slotbuf[(size_t)(blockIdx.x & 15)*4 + tid], val);
    asm volatile("" :: "v"(old));          // keep the return value live
  }
  __syncthreads();                          // drains vmcnt: slot adds complete before ctr bump
  if (tid==0){
    u32 old = atomicAdd(ctr, 1u);
    lastFlag = (old == (u32)(2*NBLK - 1)) ? 1 : 0;
  }
  __syncthreads();
  if (!lastFlag) return;

  // ---- tail block (all 256 threads): reduce slots + gamma-ppf ----
  if (w==0){
    double t0=0.0, t1=0.0, t2=0.0;
    if (lane < 16){
      double* sp = slotbuf + (size_t)lane*4;
      t0 = atomicAdd(&sp[0], 0.0);   // atomic RMW read: coherent across XCD L2s
      t1 = atomicAdd(&sp[1], 0.0);
      t2 = atomicAdd(&sp[2], 0.0);
    }
#pragma unroll
    for (int s2=1;s2<16;s2<<=1){
      t0 += __shfl_xor(t0, s2, 64);
      t1 += __shfl_xor(t1, s2, 64);
      t2 += __shfl_xor(t2, s2, 64);
    }
    if (lane==0){ stot[0]=t0; stot[1]=t1; stot[2]=t2; }
  }
  __syncthreads();
  const double n = (double)NPTS;
  double S1t=stot[0], S2t=stot[1], trVt=stot[2];
  double testStat = S1t/n;
  double varHSIC = (S2t - trVt)/n/(n-1.0);
  varHSIC = varHSIC*72.0*(n-4.0)*(n-5.0)/n/(n-1.0)/(n-2.0)/(n-3.0);
  double muX = (sK-n)/n/(n-1.0);   // trace(K) = n exactly (diag forced to 1)
  double muY = (sL-n)/n/(n-1.0);
  double mHSIC = (1.0 + muX*muY - muX - muY)/n;
  double al = mHSIC*mHSIC/varHSIC;
  double bet = varHSIC*n/mHSIC;
  double p = (double)((float)(1.0-0.8));
  double lga = lgamma(al);
  double lo = 0.0, hi = al + 10.0*sqrt(al) + 100.0;
  const double zp = -0.8416212335729142957;  // Phi^-1(0.2)
  double tt = 1.0 - 1.0/(9.0*al) + zp/(3.0*sqrt(al));
  double x = al*tt*tt*tt;
  if (!(x > 0.0) || !(x < hi)) x = 0.5*hi;
  for (int it=0; it<2; ++it){
    double P = gammainc_block4(al, x, lga, tid, lane, w, gwp, gbs);
    double diff = P - p;
    if (diff < 0.0) lo = x; else hi = x;
    if (fabs(diff) < 1e-12) break;
    double pdf = exp(-x + (al-1.0)*log(x) - lga);
    double nx = x - diff/pdf;
    if (!(nx > lo) || !(nx < hi)) nx = 0.5*(lo+hi);
    x = nx;
  }
  if (tid==0){
    out[0]=(float)testStat;
    out[1]=(float)(bet*x);
  }
}

// ---------- host ----------
extern "C" void kernel_launch(void* const* d_in, const int* in_sizes, int n_in,
                              void* d_out, int out_size, void* d_ws, size_t ws_size,
                              hipStream_t stream) {
  const float* X = (const float*)d_in[0];
  const float* Y = (const float*)d_in[1];
  float* out = (float*)d_out;
  char* ws = (char*)d_ws;

  double* sumsS    = (double*)ws;                    // 16 doubles (8 slots per z)
  float*  scal     = (float*)(ws + 128);             // 2 floats
  u32*    histsum  = (u32*)(ws + 256);               // 2*836 u32 = 6688 B
  double* slotbuf  = (double*)(ws + 7168);           // 16 slots x 4 doubles = 512 B
  u32*    ctr      = (u32*)(ws + 7680);              // done counter
  double* rowK     = (double*)(ws + 8192);           // 32 KB
  double* rowL     = (double*)(ws + 40960);          // 32 KB
  float*  Gall     = (float*)(ws + 73728);           // 32 KB
  u16*    Xbf      = (u16*)(ws + (4u<<20));          // 1 MB (swizzled fragment-major)
  size_t need = (size_t)(4u<<20) + (size_t)2*NPTS*DIM*2;   // ~5.2 MB

  if (ws_size < need) return;

  convert_k<<<64,256,0,stream>>>(X, Y, Xbf, Gall, histsum, rowK, rowL, sumsS, slotbuf, ctr);
  hist_k<<<dim3(NBLK,2),256,0,stream>>>(Xbf, Gall, histsum);
  rowsum_k<<<dim3(NBLK,2),256,0,stream>>>(Xbf, Gall, histsum, scal, rowK, rowL, sumsS);
  final_k<<<2*NBLK,256,0,stream>>>(Xbf, Gall, scal, rowK, rowL, sumsS, slotbuf, ctr, out);
}

// Round 6
// 134.743 us; speedup vs baseline: 3.5318x; 1.0730x over previous
//
#include <hip/hip_runtime.h>

typedef unsigned int u32;
typedef unsigned short u16;
typedef __attribute__((ext_vector_type(8))) short bf16x8;   // 8 bf16 in 4 VGPRs
typedef __attribute__((ext_vector_type(4))) float f32x4;

#define NPTS 4096
#define DIM  64
#define NB   32          // 4096/128
#define NBLK 528         // NB*(NB+1)/2 upper-tri 128x128 blocks
#define WLO16 0x4140u    // window low: float bits 0x41400000 = 12.0
#define NWBIN 832        // t16 in [0x4140, 0x4480) -> D in [12, 1024)
#define RSTR 836         // histogram stride in u32 (834 bins + pad)
#define LOG2E 1.4426950408889634f
// full-matrix ranks: diag(4096 zeros) + doubled upper-tri; m_ut = 8386560
#define KF1C 8390654u
#define KF2C 8390656u

// Swizzled fragment-major layout (chunk = bf16x8 = 16 B):
//   chunk_index(row, f) = (row>>4)*128 + f*16 + (row&15)

// map linear upper-tri block id -> (by,bx), bx>=by
__device__ __forceinline__ void bmap(int b, int& by, int& bx){
  by = 0;
  while (b >= NB - by){ b -= NB - by; by++; }
  bx = by + b;
}

// fp32 -> bf16 bits, round-nearest-even
__device__ __forceinline__ u16 f2bf(float x){
  u32 u = __float_as_uint(x);
  return (u16)((u + 0x7fffu + ((u>>16)&1u)) >> 16);
}

// ---------- dispatch 1: convert to swizzled bf16 + norms; zero accumulators ----------
__global__ __launch_bounds__(256) void convert_k(const float* __restrict__ X, const float* __restrict__ Y,
                                                 u16* __restrict__ Xbf, float* __restrict__ Gall,
                                                 u32* __restrict__ histsum, double* __restrict__ rowK,
                                                 double* __restrict__ rowL, double* __restrict__ sumsS,
                                                 double* __restrict__ slotbuf, u32* __restrict__ ctr){
  int t = blockIdx.x*256 + threadIdx.x;     // 16384 threads, 2 per row (half-row each)
  int rid = t >> 1, hf = t & 1;
  int z = rid >> 12, row = rid & 4095;
  const float* src = (z ? Y : X) + (size_t)row*DIM + hf*32;
  u16* basep = Xbf + ((size_t)z*32768 + (size_t)(row>>4)*128 + (row&15))*8;
  float g = 0.f;
#pragma unroll
  for (int f=0; f<4; f++){
    float4 f0 = *(const float4*)(src + f*8);
    float4 f1 = *(const float4*)(src + f*8 + 4);
    g = fmaf(f0.x,f0.x,g); g = fmaf(f0.y,f0.y,g); g = fmaf(f0.z,f0.z,g); g = fmaf(f0.w,f0.w,g);
    g = fmaf(f1.x,f1.x,g); g = fmaf(f1.y,f1.y,g); g = fmaf(f1.z,f1.z,g); g = fmaf(f1.w,f1.w,g);
    ushort4 h0, h1;
    h0.x=f2bf(f0.x); h0.y=f2bf(f0.y); h0.z=f2bf(f0.z); h0.w=f2bf(f0.w);
    h1.x=f2bf(f1.x); h1.y=f2bf(f1.y); h1.z=f2bf(f1.z); h1.w=f2bf(f1.w);
    u16* dst = basep + (size_t)(hf*4 + f)*16*8;
    *(ushort4*)dst = h0;
    *(ushort4*)(dst+4) = h1;
  }
  g += __shfl_xor(g, 1, 64);               // combine the two half-row partials
  if (hf==0) Gall[rid] = g;
  // zero atomic accumulators (workspace is re-poisoned between runs)
  if (t < NPTS){ rowK[t] = 0.0; rowL[t] = 0.0; }
  if (t < 2*RSTR) histsum[t] = 0u;
  if (t < 64) slotbuf[t] = 0.0;
  if (t < 16) sumsS[t] = 0.0;
  if (t == 0) *ctr = 0u;
}

// ---------- dispatch 2: upper-tri block histogram, LDS-staged B panel ----------
// (256,4) kept: low natural VGPR, no spill observed; R5 showed net speedup.
__global__ __launch_bounds__(256,4) void hist_k(const u16* __restrict__ Xbf, const float* __restrict__ Gall,
                                                u32* __restrict__ histsum){
  __shared__ u32 lh[4][RSTR];
  __shared__ bf16x8 sB[1024];               // 16 KB: B panel (8 row-groups x 128 chunks)
  int z = blockIdx.y, tid = threadIdx.x;
  int by,bx; bmap(blockIdx.x, by, bx);
  bool isdiag = (by==bx);
  u32 wgt = isdiag ? 1u : 2u;
  int w=tid>>6, lane=tid&63, q=lane>>4, nl=lane&15;
  int cp = lane & 3;                        // replica copy: splits same-bin serialization 4x
  const bf16x8* Xb = (const bf16x8*)Xbf + (size_t)z*32768;
  const bf16x8* srcB = Xb + (size_t)(bx*8)*128;
  for (int t=tid;t<1024;t+=256) sB[t] = srcB[t];
  for (int t=tid;t<4*RSTR;t+=256) ((u32*)lh)[t]=0;
  __syncthreads();
  const float* Gz = Gall + z*NPTS;
  int ag0 = by*8 + w, ag1 = by*8 + 4 + w;
  bf16x8 a0f0 = Xb[ag0*128 + q*16 + nl];
  bf16x8 a0f1 = Xb[ag0*128 + (4+q)*16 + nl];
  bf16x8 a1f0 = Xb[ag1*128 + q*16 + nl];
  bf16x8 a1f1 = Xb[ag1*128 + (4+q)*16 + nl];
  float ga0 = Gz[ag0*16 + nl], ga1 = Gz[ag1*16 + nl];
  float g0m[4], g1m[4];
#pragma unroll
  for (int r=0;r<4;r++){ g0m[r] = __shfl(ga0, q*4+r, 64); g1m[r] = __shfl(ga1, q*4+r, 64); }
#pragma unroll
  for (int tb=0;tb<8;tb++){
    bf16x8 bf0 = sB[tb*128 + q*16 + nl];
    bf16x8 bf1 = sB[tb*128 + (4+q)*16 + nl];
    f32x4 acc0 = (f32x4)0.0f, acc1 = (f32x4)0.0f;
    acc0 = __builtin_amdgcn_mfma_f32_16x16x32_bf16(a0f0, bf0, acc0, 0,0,0);
    acc0 = __builtin_amdgcn_mfma_f32_16x16x32_bf16(a0f1, bf1, acc0, 0,0,0);
    acc1 = __builtin_amdgcn_mfma_f32_16x16x32_bf16(a1f0, bf0, acc1, 0,0,0);
    acc1 = __builtin_amdgcn_mfma_f32_16x16x32_bf16(a1f1, bf1, acc1, 0,0,0);
    int j = (bx*8 + tb)*16 + nl;
    float gb = Gz[j];
#pragma unroll
    for (int r=0;r<4;r++){
      float d0 = (g0m[r] + gb) - 2.0f*acc0[r];
      float d1 = (g1m[r] + gb) - 2.0f*acc1[r];
      if (isdiag){
        if (ag0*16 + q*4 + r == j) d0 = 0.f;
        if (ag1*16 + q*4 + r == j) d1 = 0.f;
      }
      u32 t0 = __float_as_uint(d0) >> 16;
      u32 bin0 = (t0 < WLO16) ? 0u : (t0 >= WLO16+NWBIN) ? (u32)(NWBIN+1) : (t0 - WLO16 + 1u);
      atomicAdd(&lh[cp][bin0], wgt);
      u32 t1 = __float_as_uint(d1) >> 16;
      u32 bin1 = (t1 < WLO16) ? 0u : (t1 >= WLO16+NWBIN) ? (u32)(NWBIN+1) : (t1 - WLO16 + 1u);
      atomicAdd(&lh[cp][bin1], wgt);
    }
  }
  __syncthreads();
  u32* dst = histsum + (size_t)z*RSTR;
  for (int t=tid;t<RSTR;t+=256){
    u32 v = lh[0][t] + lh[1][t] + lh[2][t] + lh[3][t];
    if (v) atomicAdd(&dst[t], v);
  }
}

// ---------- dispatch 3: per-block median scan + upper-tri row sums (LDS-staged B) ----------
// (256,3): cap ~170 VGPR >> natural f64-heavy usage -> no spill, keeps multi-block/CU.
__global__ __launch_bounds__(256,3) void rowsum_k(const u16* __restrict__ Xbf, const float* __restrict__ Gall,
                                                  const u32* __restrict__ histsum, float* __restrict__ scal,
                                                  double* __restrict__ rowK, double* __restrict__ rowL,
                                                  double* __restrict__ sumsS){
  __shared__ union {
    struct { u32 wsum[4]; double svals[2]; float scal_sh; } sc;
    struct { double rowacc[128]; double colLDS[4][128]; double tred[2]; } rs;
  } sh;
  __shared__ bf16x8 sB[1024];               // 16 KB B panel
  int z = blockIdx.y, tid = threadIdx.x;
  int w=tid>>6, lane=tid&63, q=lane>>4, nl=lane&15;
  int by,bx; bmap(blockIdx.x, by, bx);
  bool isdiag = (by==bx);
  const bf16x8* Xb = (const bf16x8*)Xbf + (size_t)z*32768;
  const bf16x8* srcB = Xb + (size_t)(bx*8)*128;
  for (int t=tid;t<1024;t+=256) sB[t] = srcB[t];   // staging overlaps the scan prologue

  // --- scan prologue: compute median width from histsum (every block, L2 hits) ---
  {
    u32 c4[4] = {0,0,0,0};
    if (tid < 209){
      const u32* base = histsum + (size_t)z*RSTR + 4*tid;
      int lim = RSTR - 4*tid;
      c4[0] = base[0];
      if (lim>1) c4[1] = base[1];
      if (lim>2) c4[2] = base[2];
      if (lim>3) c4[3] = base[3];
    }
    u32 s = c4[0]+c4[1]+c4[2]+c4[3];
    u32 pre = s;
#pragma unroll
    for (int off=1; off<64; off<<=1){
      u32 t2 = __shfl_up(pre, off, 64);
      if (lane >= off) pre += t2;
    }
    if (lane==63) sh.sc.wsum[w] = pre;
    __syncthreads();
    u32 base2 = 0;
    for (int k=0;k<w;k++) base2 += sh.sc.wsum[k];
    u32 incl = base2 + pre, excl = incl - s;
    u32 ks[2] = {KF1C,KF2C};
#pragma unroll
    for (int w2=0; w2<2; w2++){
      if (ks[w2] >= excl && ks[w2] < incl){
        u32 acc = excl;
#pragma unroll
        for (int j=0;j<4;j++){
          if (ks[w2] < acc + c4[j]){
            int b = tid*4 + j;
            double lo, hi;
            if (b==0){ lo=12.0; hi=12.0; }
            else if (b>=NWBIN+1){ lo=1024.0; hi=1024.0; }
            else {
              u32 t16 = WLO16 + (u32)b - 1u;
              lo = (double)__uint_as_float(t16<<16);
              hi = (double)__uint_as_float((t16+1u)<<16);
            }
            double frac = ((double)(ks[w2]-acc) + 0.5)/(double)c4[j];
            sh.sc.svals[w2] = lo + (hi-lo)*frac;
            break;
          }
          acc += c4[j];
        }
      }
    }
    __syncthreads();
    if (tid==0){
      float med = (float)(0.5*(sh.sc.svals[0]+sh.sc.svals[1]));
      float wd = sqrtf(0.5f*med);
      float sc2 = 2.0f*wd*wd;
      sh.sc.scal_sh = sc2;
      if (blockIdx.x==0) scal[z] = sc2;    // for final_k
    }
    __syncthreads();
  }
  float negi = -LOG2E / sh.sc.scal_sh;      // exp(x) = exp2(x*log2e): fold into scale
  __syncthreads();                          // done reading union.sc before union.rs writes

  // --- rowsum body ---
  const float* Gz = Gall + z*NPTS;
  int ag0 = by*8 + w, ag1 = by*8 + 4 + w;
  bf16x8 a0f0 = Xb[ag0*128 + q*16 + nl];
  bf16x8 a0f1 = Xb[ag0*128 + (4+q)*16 + nl];
  bf16x8 a1f0 = Xb[ag1*128 + q*16 + nl];
  bf16x8 a1f1 = Xb[ag1*128 + (4+q)*16 + nl];
  float ga0 = Gz[ag0*16 + nl], ga1 = Gz[ag1*16 + nl];
  float g0m[4], g1m[4];
#pragma unroll
  for (int r=0;r<4;r++){ g0m[r] = __shfl(ga0, q*4+r, 64); g1m[r] = __shfl(ga1, q*4+r, 64); }
  double rs0[4] = {0,0,0,0}, rs1[4] = {0,0,0,0};
#pragma unroll
  for (int tb=0;tb<8;tb++){
    bf16x8 bf0 = sB[tb*128 + q*16 + nl];
    bf16x8 bf1 = sB[tb*128 + (4+q)*16 + nl];
    f32x4 acc0 = (f32x4)0.0f, acc1 = (f32x4)0.0f;
    acc0 = __builtin_amdgcn_mfma_f32_16x16x32_bf16(a0f0, bf0, acc0, 0,0,0);
    acc0 = __builtin_amdgcn_mfma_f32_16x16x32_bf16(a0f1, bf1, acc0, 0,0,0);
    acc1 = __builtin_amdgcn_mfma_f32_16x16x32_bf16(a1f0, bf0, acc1, 0,0,0);
    acc1 = __builtin_amdgcn_mfma_f32_16x16x32_bf16(a1f1, bf1, acc1, 0,0,0);
    int j = (bx*8 + tb)*16 + nl;
    float gb = Gz[j];
    double cs = 0.0;
#pragma unroll
    for (int r=0;r<4;r++){
      float d0 = (g0m[r] + gb) - 2.0f*acc0[r];
      float d1 = (g1m[r] + gb) - 2.0f*acc1[r];
      if (isdiag){
        if (ag0*16 + q*4 + r == j) d0 = 0.f;    // exact K_ii = 1
        if (ag1*16 + q*4 + r == j) d1 = 0.f;
      }
      double e0 = (double)exp2f(d0*negi);
      double e1 = (double)exp2f(d1*negi);
      rs0[r] += e0; rs1[r] += e1;
      cs += e0 + e1;
    }
    cs += __shfl_xor(cs, 16, 64);
    cs += __shfl_xor(cs, 32, 64);
    if (q==0) sh.rs.colLDS[w][tb*16 + nl] = cs;
  }
#pragma unroll
  for (int r=0;r<4;r++){
    double v0 = rs0[r], v1 = rs1[r];
    v0 += __shfl_xor(v0,1,64); v0 += __shfl_xor(v0,2,64);
    v0 += __shfl_xor(v0,4,64); v0 += __shfl_xor(v0,8,64);
    v1 += __shfl_xor(v1,1,64); v1 += __shfl_xor(v1,2,64);
    v1 += __shfl_xor(v1,4,64); v1 += __shfl_xor(v1,8,64);
    rs0[r] = v0; rs1[r] = v1;
  }
  if (nl==0){
#pragma unroll
    for (int r=0;r<4;r++){
      sh.rs.rowacc[w*16 + q*4 + r]     = rs0[r];
      sh.rs.rowacc[(4+w)*16 + q*4 + r] = rs1[r];
    }
  }
  __syncthreads();
  double tot = 0.0;
  if (tid < 128){
    double rv = sh.rs.rowacc[tid];
    double cv = sh.rs.colLDS[0][tid] + sh.rs.colLDS[1][tid] + sh.rs.colLDS[2][tid] + sh.rs.colLDS[3][tid];
    double* rowG = z ? rowL : rowK;
    atomicAdd(&rowG[by*128 + tid], rv);
    if (!isdiag) atomicAdd(&rowG[bx*128 + tid], cv);
    tot = rv + (isdiag ? 0.0 : cv);
  }
#pragma unroll
  for (int s2=1;s2<64;s2<<=1) tot += __shfl_xor(tot, s2, 64);
  if (lane==0 && w<2) sh.rs.tred[w] = tot;
  __syncthreads();
  if (tid==0) atomicAdd(&sumsS[z*8 + (blockIdx.x & 7)], sh.rs.tred[0] + sh.rs.tred[1]);
}

// ---------- block-parallel gamma series: 1024 terms/batch (4 per thread) ----------
__device__ double gammainc_block4(double a, double x, double lga,
                                  int tid, int lane, int w,
                                  double* wp /*shared[4]*/, double* bs /*shared[4]*/){
  double C = 1.0/a;
  double psum = 0.0;
  for (int b=0;b<512;b++){
    double k0 = (double)(b*1024 + tid*4);
    double r1 = x/(a+k0+1.0), r2 = x/(a+k0+2.0), r3 = x/(a+k0+3.0), r4 = x/(a+k0+4.0);
    double p12 = r1*r2;
    double pl = p12*(r3*r4);              // product of this thread's 4 ratios
    double pp = pl;                        // inclusive prefix across 64 lanes
#pragma unroll
    for (int s=1;s<64;s<<=1){
      double t = __shfl_up(pp, s, 64);
      if (lane >= s) pp *= t;
    }
    if (lane==63) wp[w] = pp;
    __syncthreads();
    double cross = 1.0;
    for (int k2=0;k2<w;k2++) cross *= wp[k2];
    double call = wp[0]*wp[1]*wp[2]*wp[3];
    double excl = __shfl_up(pp, 1, 64);
    if (lane==0) excl = 1.0;
    double base = C*cross*excl;            // prefix before this thread's 4 terms
    double t1 = base*r1, t2 = base*p12, t3 = t2*r3, t4 = base*pl;
    psum += (t1+t2)+(t3+t4);
    double Cn = C*call;
    C = Cn;
    double rlast = x/(a + (double)(b*1024 + 1024));
    __syncthreads();                       // wp reused next iteration
    if (rlast < 1.0 && Cn*rlast/(1.0-rlast) < 1e-17) break;
  }
#pragma unroll
  for (int s=1;s<64;s<<=1) psum += __shfl_xor(psum, s, 64);
  if (lane==0) bs[w] = psum;
  __syncthreads();
  double total = 1.0/a + bs[0]+bs[1]+bs[2]+bs[3];
  __syncthreads();
  return exp(-x + a*log(x) - lga) * total;
}

// ---------- dispatch 4: centered products (1056 half-tile blocks, LDS panels) + tail finalize ----------
// (256,2): VGPR cap 256 >> natural usage -> NO SPILL (R5's (256,4) forced 64 VGPR + 17 MB scratch).
// Occupancy comes from the grid (1056 blocks) + LDS (33 KB -> ~4 blocks/CU), not the bounds.
__global__ __launch_bounds__(256,2) void final_k(const u16* __restrict__ Xbf, const float* __restrict__ Gall,
                                                 const float* __restrict__ scal,
                                                 const double* __restrict__ rowK,
                                                 const double* __restrict__ rowL,
                                                 const double* __restrict__ sumsS,
                                                 double* __restrict__ slotbuf, u32* __restrict__ ctr,
                                                 float* __restrict__ out){
  __shared__ bf16x8 sBX[1024];              // 16 KB: X B-panel
  __shared__ bf16x8 sBY[1024];              // 16 KB: Y B-panel
  __shared__ double red[4][3];
  __shared__ double gwp[4], gbs[4], stot[3];
  __shared__ int lastFlag;
  int tid = threadIdx.x;
  int b = blockIdx.x >> 1, half = blockIdx.x & 1;
  int by,bx; bmap(b,by,bx);
  bool isdiag = (by==bx);
  int w=tid>>6, lane=tid&63, q=lane>>4, nl=lane&15;
  const bf16x8* Xb = (const bf16x8*)Xbf;
  const bf16x8* Yb = Xb + 32768;
  const bf16x8* srcBX = Xb + (size_t)(bx*8)*128;
  const bf16x8* srcBY = Yb + (size_t)(bx*8)*128;
  for (int t=tid;t<1024;t+=256){ sBX[t] = srcBX[t]; sBY[t] = srcBY[t]; }
  const float* Gx = Gall;
  const float* Gy = Gall + NPTS;
  const double inv_n = 1.0/(double)NPTS;
  double sK=0.0, sL=0.0;
#pragma unroll
  for (int k2=0;k2<8;k2++){ sK += sumsS[k2]; sL += sumsS[8+k2]; }
  double tmK = sK*(inv_n*inv_n), tmL = sL*(inv_n*inv_n);
  float negx = -LOG2E/scal[0], negy = -LOG2E/scal[1];   // exp2-folded
  double S1=0, S2=0, trV=0;                // raw sums; wgt & 1/36 hoisted to reduction
  int ag = by*8 + half*4 + w;              // this block's 4 A row-groups
  bf16x8 axf0 = Xb[ag*128 + q*16 + nl];
  bf16x8 axf1 = Xb[ag*128 + (4+q)*16 + nl];
  bf16x8 ayf0 = Yb[ag*128 + q*16 + nl];
  bf16x8 ayf1 = Yb[ag*128 + (4+q)*16 + nl];
  float gaX = Gx[ag*16 + nl], gaY = Gy[ag*16 + nl];
  float gXm[4], gYm[4];
#pragma unroll
  for (int r=0;r<4;r++){ gXm[r] = __shfl(gaX, q*4+r, 64); gYm[r] = __shfl(gaY, q*4+r, 64); }
  double rmKi[4], rmLi[4];
#pragma unroll
  for (int r=0;r<4;r++){
    int i = ag*16 + q*4 + r;
    rmKi[r] = rowK[i]*inv_n; rmLi[r] = rowL[i]*inv_n;
  }
  __syncthreads();                          // panels staged
#pragma unroll
  for (int tb=0;tb<8;tb++){
    bf16x8 bx0 = sBX[tb*128 + q*16 + nl];
    bf16x8 bx1 = sBX[tb*128 + (4+q)*16 + nl];
    bf16x8 by0 = sBY[tb*128 + q*16 + nl];
    bf16x8 by1 = sBY[tb*128 + (4+q)*16 + nl];
    f32x4 accX = (f32x4)0.0f, accY = (f32x4)0.0f;
    accX = __builtin_amdgcn_mfma_f32_16x16x32_bf16(axf0, bx0, accX, 0,0,0);
    accX = __builtin_amdgcn_mfma_f32_16x16x32_bf16(axf1, bx1, accX, 0,0,0);
    accY = __builtin_amdgcn_mfma_f32_16x16x32_bf16(ayf0, by0, accY, 0,0,0);
    accY = __builtin_amdgcn_mfma_f32_16x16x32_bf16(ayf1, by1, accY, 0,0,0);
    int j = (bx*8 + tb)*16 + nl;
    float gbX = Gx[j], gbY = Gy[j];
    double cmK = rowK[j]*inv_n - tmK;
    double cmL = rowL[j]*inv_n - tmL;
#pragma unroll
    for (int r=0;r<4;r++){
      int i = ag*16 + q*4 + r;
      float dx = (gXm[r] + gbX) - 2.0f*accX[r];
      float dy = (gYm[r] + gbY) - 2.0f*accY[r];
      bool dg = isdiag && i==j;
      if (dg){ dx = 0.f; dy = 0.f; }
      float kx = exp2f(dx*negx);
      float lv = exp2f(dy*negy);
      double kc = ((double)kx - rmKi[r]) - cmK;
      double lc = ((double)lv - rmLi[r]) - cmL;
      double prod = kc*lc;
      S1 += prod;
      S2 = fma(prod, prod, S2);
      if (dg) trV = fma(prod, prod, trV);
    }
  }
  {
    double wgt = isdiag ? 1.0 : 2.0;
    S1 *= wgt;
    S2 *= wgt*(1.0/36.0);
    trV *= (1.0/36.0);
  }
  double vals[3]={S1,S2,trV};
#pragma unroll
  for (int v=0;v<3;v++){
    double x = vals[v];
#pragma unroll
    for (int s2=1;s2<64;s2<<=1) x += __shfl_xor(x, s2, 64);
    if (lane==0) red[w][v]=x;
  }
  __syncthreads();
  if (tid < 3){
    double val = red[0][tid]+red[1][tid]+red[2][tid]+red[3][tid];
    // returning atomic: completion (not just issue) before the barrier's vmcnt drain
    double old = atomicAdd(&slotbuf[(size_t)(blockIdx.x & 15)*4 + tid], val);
    asm volatile("" :: "v"(old));          // keep the return value live
  }
  __syncthreads();                          // drains vmcnt: slot adds complete before ctr bump
  if (tid==0){
    u32 old = atomicAdd(ctr, 1u);
    lastFlag = (old == (u32)(2*NBLK - 1)) ? 1 : 0;
  }
  __syncthreads();
  if (!lastFlag) return;

  // ---- tail block (all 256 threads): reduce slots + gamma-ppf ----
  if (w==0){
    double t0=0.0, t1=0.0, t2=0.0;
    if (lane < 16){
      double* sp = slotbuf + (size_t)lane*4;
      t0 = atomicAdd(&sp[0], 0.0);   // atomic RMW read: coherent across XCD L2s
      t1 = atomicAdd(&sp[1], 0.0);
      t2 = atomicAdd(&sp[2], 0.0);
    }
#pragma unroll
    for (int s2=1;s2<16;s2<<=1){
      t0 += __shfl_xor(t0, s2, 64);
      t1 += __shfl_xor(t1, s2, 64);
      t2 += __shfl_xor(t2, s2, 64);
    }
    if (lane==0){ stot[0]=t0; stot[1]=t1; stot[2]=t2; }
  }
  __syncthreads();
  const double n = (double)NPTS;
  double S1t=stot[0], S2t=stot[1], trVt=stot[2];
  double testStat = S1t/n;
  double varHSIC = (S2t - trVt)/n/(n-1.0);
  varHSIC = varHSIC*72.0*(n-4.0)*(n-5.0)/n/(n-1.0)/(n-2.0)/(n-3.0);
  double muX = (sK-n)/n/(n-1.0);   // trace(K) = n exactly (diag forced to 1)
  double muY = (sL-n)/n/(n-1.0);
  double mHSIC = (1.0 + muX*muY - muX - muY)/n;
  double al = mHSIC*mHSIC/varHSIC;
  double bet = varHSIC*n/mHSIC;
  double p = (double)((float)(1.0-0.8));
  double lga = lgamma(al);
  double lo = 0.0, hi = al + 10.0*sqrt(al) + 100.0;
  const double zp = -0.8416212335729142957;  // Phi^-1(0.2)
  double tt = 1.0 - 1.0/(9.0*al) + zp/(3.0*sqrt(al));
  double x = al*tt*tt*tt;
  if (!(x > 0.0) || !(x < hi)) x = 0.5*hi;
  for (int it=0; it<2; ++it){
    double P = gammainc_block4(al, x, lga, tid, lane, w, gwp, gbs);
    double diff = P - p;
    if (diff < 0.0) lo = x; else hi = x;
    if (fabs(diff) < 1e-12) break;
    double pdf = exp(-x + (al-1.0)*log(x) - lga);
    double nx = x - diff/pdf;
    if (!(nx > lo) || !(nx < hi)) nx = 0.5*(lo+hi);
    x = nx;
  }
  if (tid==0){
    out[0]=(float)testStat;
    out[1]=(float)(bet*x);
  }
}

// ---------- host ----------
extern "C" void kernel_launch(void* const* d_in, const int* in_sizes, int n_in,
                              void* d_out, int out_size, void* d_ws, size_t ws_size,
                              hipStream_t stream) {
  const float* X = (const float*)d_in[0];
  const float* Y = (const float*)d_in[1];
  float* out = (float*)d_out;
  char* ws = (char*)d_ws;

  double* sumsS    = (double*)ws;                    // 16 doubles (8 slots per z)
  float*  scal     = (float*)(ws + 128);             // 2 floats
  u32*    histsum  = (u32*)(ws + 256);               // 2*836 u32 = 6688 B
  double* slotbuf  = (double*)(ws + 7168);           // 16 slots x 4 doubles = 512 B
  u32*    ctr      = (u32*)(ws + 7680);              // done counter
  double* rowK     = (double*)(ws + 8192);           // 32 KB
  double* rowL     = (double*)(ws + 40960);          // 32 KB
  float*  Gall     = (float*)(ws + 73728);           // 32 KB
  u16*    Xbf      = (u16*)(ws + (4u<<20));          // 1 MB (swizzled fragment-major)
  size_t need = (size_t)(4u<<20) + (size_t)2*NPTS*DIM*2;   // ~5.2 MB

  if (ws_size < need) return;

  convert_k<<<64,256,0,stream>>>(X, Y, Xbf, Gall, histsum, rowK, rowL, sumsS, slotbuf, ctr);
  hist_k<<<dim3(NBLK,2),256,0,stream>>>(Xbf, Gall, histsum);
  rowsum_k<<<dim3(NBLK,2),256,0,stream>>>(Xbf, Gall, histsum, scal, rowK, rowL, sumsS);
  final_k<<<2*NBLK,256,0,stream>>>(Xbf, Gall, scal, rowK, rowL, sumsS, slotbuf, ctr, out);
}